// Round 13
// baseline (159.820 us; speedup 1.0000x reference)
//
#include <hip/hip_runtime.h>
#include <hip/hip_bf16.h>
#include <stdint.h>

#define N_NODES 50000
#define N_EDGES 1000000
#define HIDDEN 128

using short8  = __attribute__((ext_vector_type(8))) short;
using floatx4 = __attribute__((ext_vector_type(4))) float;
using floatx2 = __attribute__((ext_vector_type(2))) float;

__device__ __forceinline__ float bf2f(uint16_t u) {
    return __uint_as_float(((uint32_t)u) << 16);
}
__device__ __forceinline__ uint16_t f2bf(float f) {
    uint32_t x = __float_as_uint(f);
    return (uint16_t)((x + 0x7FFFu + ((x >> 16) & 1u)) >> 16);
}
__device__ __forceinline__ uint32_t cvt_pk_bf16(float lo, float hi) {
    uint32_t r;
    asm("v_cvt_pk_bf16_f32 %0, %1, %2" : "=v"(r) : "v"(lo), "v"(hi));
    return r;
}
__device__ __forceinline__ float fast_silu(float x) {
    float e = __expf(-x);
    return x * __builtin_amdgcn_rcpf(1.0f + e);
}
// one f32 -> one fp8 e4m3 byte (gfx950 OCP format)
__device__ __forceinline__ uint8_t f2fp8(float v) {
    uint32_t p = __builtin_amdgcn_cvt_pk_fp8_f32(v, v, 0u, false);
    return (uint8_t)(p & 0xffu);
}
// unpack 8 fp8 bytes (two u32 words) -> 8 f32
__device__ __forceinline__ void fp8_unpack8(uint32_t w0, uint32_t w1, float f[8]) {
    floatx2 p;
    p = __builtin_amdgcn_cvt_pk_f32_fp8(w0, false); f[0] = p[0]; f[1] = p[1];
    p = __builtin_amdgcn_cvt_pk_f32_fp8(w0, true);  f[2] = p[0]; f[3] = p[1];
    p = __builtin_amdgcn_cvt_pk_f32_fp8(w1, false); f[4] = p[0]; f[5] = p[1];
    p = __builtin_amdgcn_cvt_pk_f32_fp8(w1, true);  f[6] = p[0]; f[7] = p[1];
}

// channel permutation for At/Bt storage: c = kk*32 + kg*8 + j  ->  kg*32 + kk*8 + j
__device__ __forceinline__ int perm_c(int c) {
    return ((c >> 3) & 3) * 32 + ((c >> 5) << 3) + (c & 7);
}

// DPP rotate-add within each 16-lane row (pure VALU, no LDS pipe)
template <int CTRL>
__device__ __forceinline__ float row_ror_add(float v) {
    return v + __int_as_float(__builtin_amdgcn_update_dpp(
        0, __float_as_int(v), CTRL, 0xf, 0xf, false));
}
#define REDUCE16(v)                  \
    v = row_ror_add<0x121>(v);       \
    v = row_ror_add<0x122>(v);       \
    v = row_ror_add<0x124>(v);       \
    v = row_ror_add<0x128>(v);

// ---------------------------------------------------------------------------
// Kernel 1: At[n][k] -> fp8, Bt[n][k] -> fp8 (perm_c channel order).
// 256 nodes/block (4 groups of 64) to amortize the 64KB W1 staging.
// ---------------------------------------------------------------------------
__global__ __launch_bounds__(256) void precompute_AB(
    const float* __restrict__ h, const float* __restrict__ W1,
    const float* __restrict__ b1,
    uint8_t* __restrict__ At, uint8_t* __restrict__ Bt)
{
    __shared__ uint16_t w1t[256 * 128];  // [c][j] bf16, XOR-swizzled, 64 KB
    int t = threadIdx.x;
    for (int idx = t; idx < 256 * 128; idx += 256) {
        int c = idx >> 7, j = idx & 127;
        float v = (c < 128) ? W1[j * 128 + c] : W1[(128 + j) * 128 + (c - 128)];
        int byte_off = (c << 8) + (j << 1);
        byte_off ^= ((c & 7) << 4);
        *(uint16_t*)((char*)w1t + byte_off) = f2bf(v);
    }
    __syncthreads();

    int wave = t >> 6, lane = t & 63;
    int lrow = lane & 15, kg = lane >> 4;

    for (int g = 0; g < 4; ++g) {
        int nodeBase = blockIdx.x * 256 + g * 64 + wave * 16;
        if (nodeBase >= N_NODES) break;
        int node = nodeBase + lrow;
        int nclamp = node < N_NODES ? node : N_NODES - 1;
        const float* hrow = h + (size_t)nclamp * 128;

        short8 afrag[4];
#pragma unroll
        for (int kk = 0; kk < 4; ++kk) {
            int k0 = kk * 32 + kg * 8;
            float4 f0 = *(const float4*)(hrow + k0);
            float4 f1 = *(const float4*)(hrow + k0 + 4);
            short8 a;
            uint32_t* ap = (uint32_t*)&a;
            ap[0] = cvt_pk_bf16(f0.x, f0.y);
            ap[1] = cvt_pk_bf16(f0.z, f0.w);
            ap[2] = cvt_pk_bf16(f1.x, f1.y);
            ap[3] = cvt_pk_bf16(f1.z, f1.w);
            afrag[kk] = a;
        }

        for (int nt = 0; nt < 16; ++nt) {
            floatx4 acc = {0.f, 0.f, 0.f, 0.f};
            int c = nt * 16 + lrow;
#pragma unroll
            for (int kk = 0; kk < 4; ++kk) {
                int byte_off = (c << 8) + ((kk * 32 + kg * 8) << 1);
                byte_off ^= ((c & 7) << 4);
                short8 b = *(const short8*)((const char*)w1t + byte_off);
                acc = __builtin_amdgcn_mfma_f32_16x16x32_bf16(afrag[kk], b, acc, 0, 0, 0);
            }
#pragma unroll
            for (int r = 0; r < 4; ++r) {
                int onode = nodeBase + kg * 4 + r;
                if (onode < N_NODES) {
                    float v = acc[r];
                    if (c < 128) {
                        At[(size_t)onode * 128 + perm_c(c)] = f2fp8(v + b1[c]);
                    } else {
                        int cc = c - 128;
                        Bt[(size_t)onode * 128 + perm_c(cc)] = f2fp8(v);
                    }
                }
            }
        }
    }
}

// ---------------------------------------------------------------------------
// Kernel 2: per-edge fused MLP (round-12 structure) + hoisted epilogue loads.
// coord_diff/edge_mask (streaming HBM, ~600-900 cyc) were loaded inside the
// end-of-half epilogue -> up to ~1400 cyc exposed stall per pair. Now loaded
// at pair top (clamped indices, all lanes) so they fly under the MLP compute.
// LDS index prefetch via global_load_lds ping-pong (round 12). VGPR <=64.
// ---------------------------------------------------------------------------
__global__ __launch_bounds__(512) void edge_kernel(
    const int* __restrict__ rowIdx, const int* __restrict__ colIdx,
    const float* __restrict__ edge_attr, const float* __restrict__ edge_mask,
    const float* __restrict__ coord_diff,
    const float* __restrict__ W1, const float* __restrict__ W2,
    const float* __restrict__ b2, const float* __restrict__ W3,
    const uint8_t* __restrict__ At, const uint8_t* __restrict__ Bt,
    float* __restrict__ agg)
{
    __shared__ uint16_t w2t[128 * 128];          // [nt][kk][lane][8] bf16, 32 KB
    __shared__ float s_w1e[128], s_b2[128], s_w3[128];
    __shared__ int s_idx[2][8][64];              // [buf][wave][0-31 row | 32-63 col], 4 KB
    int t = threadIdx.x;
    for (int idx = t; idx < 128 * 128; idx += 512) {
        int j    = idx & 7;
        int ln   = (idx >> 3) & 63;
        int kkq  = (idx >> 9) & 3;
        int ntq  = idx >> 11;
        int n = ntq * 16 + (ln & 15);
        int k = kkq * 32 + (ln >> 4) * 8 + j;
        w2t[idx] = f2bf(W2[k * 128 + n]);
    }
    if (t < 128) { s_w1e[t] = W1[256 * 128 + t]; s_b2[t] = b2[t]; s_w3[t] = W3[t]; }
    __syncthreads();

    int wave = t >> 6, lane = t & 63;
    int lrow = lane & 15, kg = lane >> 4;

    const int numPairs = N_EDGES / 32;           // 31250
    int wavesTotal = gridDim.x * 8;
    int waveId = blockIdx.x * 8 + wave;
    if (waveId >= numPairs) return;

    // per-lane epilogue geometry (loop-invariant)
    int rsel = lrow / 3;                         // 0..5 (only 0..3 used)
    int dim  = lrow - rsel * 3;

    // ---- prologue: prefetch pair-0 indices into buf 0, wait once ----
    {
        int eb0 = waveId * 32;
        const int* gsrc = (lane < 32) ? (rowIdx + eb0 + lane)
                                      : (colIdx + eb0 + (lane & 31));
        __builtin_amdgcn_global_load_lds(
            (const __attribute__((address_space(1))) void*)gsrc,
            (__attribute__((address_space(3))) void*)&s_idx[0][wave][0], 4, 0, 0);
        __builtin_amdgcn_s_waitcnt(0x0F70);      // vmcnt(0)
    }

    int buf = 0;
    for (int pair = waveId; pair < numPairs; pair += wavesTotal) {
        // wait current buf's prefetch (skip the 2 in-flight atomics)
        __builtin_amdgcn_s_waitcnt(0x0F72);      // vmcnt(2)
        __builtin_amdgcn_sched_barrier(0);
        const int* mi = &s_idx[buf][wave][0];
        int r0 = mi[lrow],      c0 = mi[32 + lrow];
        int r1 = mi[16 + lrow], c1 = mi[48 + lrow];

        // prefetch next pair into the other buffer
        int nextp = pair + wavesTotal;
        if (nextp < numPairs) {
            int ebn = nextp * 32;
            const int* gsrc = (lane < 32) ? (rowIdx + ebn + lane)
                                          : (colIdx + ebn + (lane & 31));
            __builtin_amdgcn_global_load_lds(
                (const __attribute__((address_space(1))) void*)gsrc,
                (__attribute__((address_space(3))) void*)&s_idx[buf ^ 1][wave][0], 4, 0, 0);
        }

        int ebase0 = pair * 32;
        int ebase1 = ebase0 + 16;
        float attr0 = edge_attr[ebase0 + lrow];
        float attr1 = edge_attr[ebase1 + lrow];

        // ---- hoisted epilogue operands (all lanes, clamped; used if lrow<12) ----
        int sidx = kg * 4 + rsel;                        // 0..19; valid slot 0..15
        int eg0 = ebase0 + sidx;
        int eg1 = ebase1 + sidx;
        int eg0c = eg0 < N_EDGES - 1 ? eg0 : N_EDGES - 1;
        int eg1c = eg1 < N_EDGES - 1 ? eg1 : N_EDGES - 1;
        float cd0 = coord_diff[eg0c * 3 + dim];
        float em0 = edge_mask[eg0c];
        float cd1 = coord_diff[eg1c * 3 + dim];
        float em1 = edge_mask[eg1c];
        int sclamp = sidx < 16 ? sidx : 15;
        int rn0 = mi[sclamp];
        int rn1 = mi[16 + sclamp];

        // ---- all 8 gathers up front (half-0 first) ----
        const uint8_t* ar0 = At + (size_t)r0 * 128 + kg * 32;
        const uint8_t* br0 = Bt + (size_t)c0 * 128 + kg * 32;
        const uint8_t* ar1 = At + (size_t)r1 * 128 + kg * 32;
        const uint8_t* br1 = Bt + (size_t)c1 * 128 + kg * 32;
        uint4 la0 = *(const uint4*)(ar0);
        uint4 ha0 = *(const uint4*)(ar0 + 16);
        uint4 lb0 = *(const uint4*)(br0);
        uint4 hb0 = *(const uint4*)(br0 + 16);
        uint4 la1 = *(const uint4*)(ar1);
        uint4 ha1 = *(const uint4*)(ar1 + 16);
        uint4 lb1 = *(const uint4*)(br1);
        uint4 hb1 = *(const uint4*)(br1 + 16);

#pragma unroll
        for (int half = 0; half < 2; ++half) {
            float attr = half ? attr1 : attr0;
            uint4 la = half ? la1 : la0, ha = half ? ha1 : ha0;
            uint4 lb = half ? lb1 : lb0, hb = half ? hb1 : hb0;

            // ---- layer 1: fp8 rows -> silu'd bf16 A-fragments ----
            short8 afrag[4];
#pragma unroll
            for (int kk = 0; kk < 4; ++kk) {
                int k0 = kk * 32 + kg * 8;
                uint32_t wa0 = (kk == 0) ? la.x : (kk == 1) ? la.z : (kk == 2) ? ha.x : ha.z;
                uint32_t wa1 = (kk == 0) ? la.y : (kk == 1) ? la.w : (kk == 2) ? ha.y : ha.w;
                uint32_t wb0 = (kk == 0) ? lb.x : (kk == 1) ? lb.z : (kk == 2) ? hb.x : hb.z;
                uint32_t wb1 = (kk == 0) ? lb.y : (kk == 1) ? lb.w : (kk == 2) ? hb.y : hb.w;
                float fa[8], fb[8];
                fp8_unpack8(wa0, wa1, fa);
                fp8_unpack8(wb0, wb1, fb);
                float xs[8];
#pragma unroll
                for (int j = 0; j < 8; ++j) {
                    xs[j] = fast_silu(fa[j] + fb[j] + attr * s_w1e[k0 + j]);
                }
                uint32_t* up = (uint32_t*)&afrag[kk];
                up[0] = cvt_pk_bf16(xs[0], xs[1]);
                up[1] = cvt_pk_bf16(xs[2], xs[3]);
                up[2] = cvt_pk_bf16(xs[4], xs[5]);
                up[3] = cvt_pk_bf16(xs[6], xs[7]);
            }

            // ---- layer 2 + fused silu + W3 dot (b2 folded into C) ----
            float pm0 = 0.f, pm1 = 0.f, pm2 = 0.f, pm3 = 0.f;
#pragma unroll
            for (int nt = 0; nt < 8; ++nt) {
                int n = nt * 16 + lrow;
                float b2v = s_b2[n];
                floatx4 acc = {b2v, b2v, b2v, b2v};
#pragma unroll
                for (int kk = 0; kk < 4; ++kk) {
                    const short8* bp = (const short8*)(w2t + (((nt * 4 + kk) * 64 + lane) << 3));
                    acc = __builtin_amdgcn_mfma_f32_16x16x32_bf16(afrag[kk], *bp, acc, 0, 0, 0);
                }
                float w3v = s_w3[n];
                pm0 += fast_silu(acc[0]) * w3v;
                pm1 += fast_silu(acc[1]) * w3v;
                pm2 += fast_silu(acc[2]) * w3v;
                pm3 += fast_silu(acc[3]) * w3v;
            }

            // rotate-reduce across the 16-lane row (DPP, pure VALU)
            REDUCE16(pm0);
            REDUCE16(pm1);
            REDUCE16(pm2);
            REDUCE16(pm3);
            // group kg holds m for edges ebase + kg*4 + {0..3} in pm0..pm3

            if (lrow < 12) {
                float mval = (rsel == 0) ? pm0 : (rsel == 1) ? pm1
                           : (rsel == 2) ? pm2 : pm3;
                float cd = half ? cd1 : cd0;
                float em = half ? em1 : em0;
                int rnode = half ? rn1 : rn0;
                float val = cd * mval * em;
                atomicAdd(&agg[rnode * 3 + dim], val);
            }
        }
        buf ^= 1;
    }
}

// ---------------------------------------------------------------------------
// Kernel 3: out = (coord + agg/100) * node_mask
// ---------------------------------------------------------------------------
__global__ __launch_bounds__(256) void finalize_kernel(
    const float* __restrict__ coord, const float* __restrict__ agg,
    const float* __restrict__ node_mask, float* __restrict__ out)
{
    int i = blockIdx.x * 256 + threadIdx.x;
    if (i < N_NODES * 3) {
        out[i] = (coord[i] + agg[i] * 0.01f) * node_mask[i / 3];
    }
}

extern "C" void kernel_launch(void* const* d_in, const int* in_sizes, int n_in,
                              void* d_out, int out_size, void* d_ws, size_t ws_size,
                              hipStream_t stream) {
    const float* h          = (const float*)d_in[0];
    const float* coord      = (const float*)d_in[1];
    const int*   eidx       = (const int*)d_in[2];   // [2][N_EDGES] int32
    const float* coord_diff = (const float*)d_in[3];
    const float* edge_attr  = (const float*)d_in[4];
    const float* node_mask  = (const float*)d_in[5];
    const float* edge_mask  = (const float*)d_in[6];
    const float* W1 = (const float*)d_in[7];
    const float* b1 = (const float*)d_in[8];
    const float* W2 = (const float*)d_in[9];
    const float* b2 = (const float*)d_in[10];
    const float* W3 = (const float*)d_in[11];
    float* out = (float*)d_out;

    uint8_t* At = (uint8_t*)d_ws;                          // 6.4 MB
    uint8_t* Bt = At + (size_t)N_NODES * 128;              // 6.4 MB
    float*  agg = (float*)(Bt + (size_t)N_NODES * 128);    // 600 KB

    hipMemsetAsync(agg, 0, N_NODES * 3 * sizeof(float), stream);

    precompute_AB<<<(N_NODES + 255) / 256, 256, 0, stream>>>(h, W1, b1, At, Bt);

    edge_kernel<<<1024, 512, 0, stream>>>(eidx, eidx + N_EDGES, edge_attr, edge_mask,
                                          coord_diff, W1, W2, b2, W3, At, Bt, agg);

    finalize_kernel<<<(N_NODES * 3 + 255) / 256, 256, 0, stream>>>(coord, agg, node_mask, out);
}

// Round 14
// 158.645 us; speedup vs baseline: 1.0074x; 1.0074x over previous
//
#include <hip/hip_runtime.h>
#include <hip/hip_bf16.h>
#include <stdint.h>

#define N_NODES 50000
#define N_EDGES 1000000
#define HIDDEN 128

using short8  = __attribute__((ext_vector_type(8))) short;
using floatx4 = __attribute__((ext_vector_type(4))) float;
using floatx2 = __attribute__((ext_vector_type(2))) float;

__device__ __forceinline__ float bf2f(uint16_t u) {
    return __uint_as_float(((uint32_t)u) << 16);
}
__device__ __forceinline__ uint16_t f2bf(float f) {
    uint32_t x = __float_as_uint(f);
    return (uint16_t)((x + 0x7FFFu + ((x >> 16) & 1u)) >> 16);
}
__device__ __forceinline__ uint32_t cvt_pk_bf16(float lo, float hi) {
    uint32_t r;
    asm("v_cvt_pk_bf16_f32 %0, %1, %2" : "=v"(r) : "v"(lo), "v"(hi));
    return r;
}
__device__ __forceinline__ float fast_silu(float x) {
    float e = __expf(-x);
    return x * __builtin_amdgcn_rcpf(1.0f + e);
}
// one f32 -> one fp8 e4m3 byte (gfx950 OCP format)
__device__ __forceinline__ uint8_t f2fp8(float v) {
    uint32_t p = __builtin_amdgcn_cvt_pk_fp8_f32(v, v, 0u, false);
    return (uint8_t)(p & 0xffu);
}
// unpack 8 fp8 bytes (two u32 words) -> 8 f32
__device__ __forceinline__ void fp8_unpack8(uint32_t w0, uint32_t w1, float f[8]) {
    floatx2 p;
    p = __builtin_amdgcn_cvt_pk_f32_fp8(w0, false); f[0] = p[0]; f[1] = p[1];
    p = __builtin_amdgcn_cvt_pk_f32_fp8(w0, true);  f[2] = p[0]; f[3] = p[1];
    p = __builtin_amdgcn_cvt_pk_f32_fp8(w1, false); f[4] = p[0]; f[5] = p[1];
    p = __builtin_amdgcn_cvt_pk_f32_fp8(w1, true);  f[6] = p[0]; f[7] = p[1];
}

// channel permutation for At/Bt storage: c = kk*32 + kg*8 + j  ->  kg*32 + kk*8 + j
__device__ __forceinline__ int perm_c(int c) {
    return ((c >> 3) & 3) * 32 + ((c >> 5) << 3) + (c & 7);
}

// DPP rotate-add within each 16-lane row (pure VALU, no LDS pipe)
template <int CTRL>
__device__ __forceinline__ float row_ror_add(float v) {
    return v + __int_as_float(__builtin_amdgcn_update_dpp(
        0, __float_as_int(v), CTRL, 0xf, 0xf, false));
}
#define REDUCE16(v)                  \
    v = row_ror_add<0x121>(v);       \
    v = row_ror_add<0x122>(v);       \
    v = row_ror_add<0x124>(v);       \
    v = row_ror_add<0x128>(v);

// ---------------------------------------------------------------------------
// Kernel 1: At[n][k] -> fp8, Bt[n][k] -> fp8 (perm_c channel order).
// ---------------------------------------------------------------------------
__global__ __launch_bounds__(256) void precompute_AB(
    const float* __restrict__ h, const float* __restrict__ W1,
    const float* __restrict__ b1,
    uint8_t* __restrict__ At, uint8_t* __restrict__ Bt)
{
    __shared__ uint16_t w1t[256 * 128];  // [c][j] bf16, XOR-swizzled, 64 KB
    int t = threadIdx.x;
    for (int idx = t; idx < 256 * 128; idx += 256) {
        int c = idx >> 7, j = idx & 127;
        float v = (c < 128) ? W1[j * 128 + c] : W1[(128 + j) * 128 + (c - 128)];
        int byte_off = (c << 8) + (j << 1);
        byte_off ^= ((c & 7) << 4);
        *(uint16_t*)((char*)w1t + byte_off) = f2bf(v);
    }
    __syncthreads();

    int wave = t >> 6, lane = t & 63;
    int lrow = lane & 15, kg = lane >> 4;

    for (int g = 0; g < 4; ++g) {
        int nodeBase = blockIdx.x * 256 + g * 64 + wave * 16;
        if (nodeBase >= N_NODES) break;
        int node = nodeBase + lrow;
        int nclamp = node < N_NODES ? node : N_NODES - 1;
        const float* hrow = h + (size_t)nclamp * 128;

        short8 afrag[4];
#pragma unroll
        for (int kk = 0; kk < 4; ++kk) {
            int k0 = kk * 32 + kg * 8;
            float4 f0 = *(const float4*)(hrow + k0);
            float4 f1 = *(const float4*)(hrow + k0 + 4);
            short8 a;
            uint32_t* ap = (uint32_t*)&a;
            ap[0] = cvt_pk_bf16(f0.x, f0.y);
            ap[1] = cvt_pk_bf16(f0.z, f0.w);
            ap[2] = cvt_pk_bf16(f1.x, f1.y);
            ap[3] = cvt_pk_bf16(f1.z, f1.w);
            afrag[kk] = a;
        }

        for (int nt = 0; nt < 16; ++nt) {
            floatx4 acc = {0.f, 0.f, 0.f, 0.f};
            int c = nt * 16 + lrow;
#pragma unroll
            for (int kk = 0; kk < 4; ++kk) {
                int byte_off = (c << 8) + ((kk * 32 + kg * 8) << 1);
                byte_off ^= ((c & 7) << 4);
                short8 b = *(const short8*)((const char*)w1t + byte_off);
                acc = __builtin_amdgcn_mfma_f32_16x16x32_bf16(afrag[kk], b, acc, 0, 0, 0);
            }
#pragma unroll
            for (int r = 0; r < 4; ++r) {
                int onode = nodeBase + kg * 4 + r;
                if (onode < N_NODES) {
                    float v = acc[r];
                    if (c < 128) {
                        At[(size_t)onode * 128 + perm_c(c)] = f2fp8(v + b1[c]);
                    } else {
                        int cc = c - 128;
                        Bt[(size_t)onode * 128 + perm_c(cc)] = f2fp8(v);
                    }
                }
            }
        }
    }
}

// ---------------------------------------------------------------------------
// Kernel 2: per-edge fused MLP. 1024-thread blocks: 16 waves share ONE 32KB
// w2t -> block LDS ~42KB -> 2 blocks/CU -> 32 waves/CU (the full wave cap;
// 512-thr blocks capped at 16 waves/CU via 4x38.4KB LDS). VGPR ~44 <= 64 so
// the register file sustains 8 waves/SIMD. Round-12/13 structure otherwise.
// ---------------------------------------------------------------------------
__global__ __launch_bounds__(1024) void edge_kernel(
    const int* __restrict__ rowIdx, const int* __restrict__ colIdx,
    const float* __restrict__ edge_attr, const float* __restrict__ edge_mask,
    const float* __restrict__ coord_diff,
    const float* __restrict__ W1, const float* __restrict__ W2,
    const float* __restrict__ b2, const float* __restrict__ W3,
    const uint8_t* __restrict__ At, const uint8_t* __restrict__ Bt,
    float* __restrict__ agg)
{
    __shared__ uint16_t w2t[128 * 128];          // [nt][kk][lane][8] bf16, 32 KB
    __shared__ float s_w1e[128], s_b2[128], s_w3[128];
    __shared__ int s_idx[2][16][64];             // [buf][wave][0-31 row | 32-63 col], 8 KB
    int t = threadIdx.x;
    for (int idx = t; idx < 128 * 128; idx += 1024) {
        int j    = idx & 7;
        int ln   = (idx >> 3) & 63;
        int kkq  = (idx >> 9) & 3;
        int ntq  = idx >> 11;
        int n = ntq * 16 + (ln & 15);
        int k = kkq * 32 + (ln >> 4) * 8 + j;
        w2t[idx] = f2bf(W2[k * 128 + n]);
    }
    if (t < 128) { s_w1e[t] = W1[256 * 128 + t]; s_b2[t] = b2[t]; s_w3[t] = W3[t]; }
    __syncthreads();

    int wave = t >> 6, lane = t & 63;
    int lrow = lane & 15, kg = lane >> 4;

    const int numPairs = N_EDGES / 32;           // 31250
    int wavesTotal = gridDim.x * 16;
    int waveId = blockIdx.x * 16 + wave;
    if (waveId >= numPairs) return;

    // per-lane epilogue geometry (loop-invariant)
    int rsel = lrow / 3;                         // 0..5 (only 0..3 used)
    int dim  = lrow - rsel * 3;

    // ---- prologue: prefetch pair-0 indices into buf 0, wait once ----
    {
        int eb0 = waveId * 32;
        const int* gsrc = (lane < 32) ? (rowIdx + eb0 + lane)
                                      : (colIdx + eb0 + (lane & 31));
        __builtin_amdgcn_global_load_lds(
            (const __attribute__((address_space(1))) void*)gsrc,
            (__attribute__((address_space(3))) void*)&s_idx[0][wave][0], 4, 0, 0);
        __builtin_amdgcn_s_waitcnt(0x0F70);      // vmcnt(0)
    }

    int buf = 0;
    for (int pair = waveId; pair < numPairs; pair += wavesTotal) {
        // wait current buf's prefetch (skip the 2 in-flight atomics)
        __builtin_amdgcn_s_waitcnt(0x0F72);      // vmcnt(2)
        __builtin_amdgcn_sched_barrier(0);
        const int* mi = &s_idx[buf][wave][0];
        int r0 = mi[lrow],      c0 = mi[32 + lrow];
        int r1 = mi[16 + lrow], c1 = mi[48 + lrow];

        // prefetch next pair into the other buffer
        int nextp = pair + wavesTotal;
        if (nextp < numPairs) {
            int ebn = nextp * 32;
            const int* gsrc = (lane < 32) ? (rowIdx + ebn + lane)
                                          : (colIdx + ebn + (lane & 31));
            __builtin_amdgcn_global_load_lds(
                (const __attribute__((address_space(1))) void*)gsrc,
                (__attribute__((address_space(3))) void*)&s_idx[buf ^ 1][wave][0], 4, 0, 0);
        }

        int ebase0 = pair * 32;
        int ebase1 = ebase0 + 16;
        float attr0 = edge_attr[ebase0 + lrow];
        float attr1 = edge_attr[ebase1 + lrow];

        // ---- hoisted epilogue operands (all lanes, clamped; used if lrow<12) ----
        int sidx = kg * 4 + rsel;                        // 0..19; valid slot 0..15
        int eg0 = ebase0 + sidx;
        int eg1 = ebase1 + sidx;
        int eg0c = eg0 < N_EDGES - 1 ? eg0 : N_EDGES - 1;
        int eg1c = eg1 < N_EDGES - 1 ? eg1 : N_EDGES - 1;
        float cd0 = coord_diff[eg0c * 3 + dim];
        float em0 = edge_mask[eg0c];
        float cd1 = coord_diff[eg1c * 3 + dim];
        float em1 = edge_mask[eg1c];
        int sclamp = sidx < 16 ? sidx : 15;
        int rn0 = mi[sclamp];
        int rn1 = mi[16 + sclamp];

        // ---- all 8 gathers up front (half-0 first) ----
        const uint8_t* ar0 = At + (size_t)r0 * 128 + kg * 32;
        const uint8_t* br0 = Bt + (size_t)c0 * 128 + kg * 32;
        const uint8_t* ar1 = At + (size_t)r1 * 128 + kg * 32;
        const uint8_t* br1 = Bt + (size_t)c1 * 128 + kg * 32;
        uint4 la0 = *(const uint4*)(ar0);
        uint4 ha0 = *(const uint4*)(ar0 + 16);
        uint4 lb0 = *(const uint4*)(br0);
        uint4 hb0 = *(const uint4*)(br0 + 16);
        uint4 la1 = *(const uint4*)(ar1);
        uint4 ha1 = *(const uint4*)(ar1 + 16);
        uint4 lb1 = *(const uint4*)(br1);
        uint4 hb1 = *(const uint4*)(br1 + 16);

#pragma unroll
        for (int half = 0; half < 2; ++half) {
            float attr = half ? attr1 : attr0;
            uint4 la = half ? la1 : la0, ha = half ? ha1 : ha0;
            uint4 lb = half ? lb1 : lb0, hb = half ? hb1 : hb0;

            // ---- layer 1: fp8 rows -> silu'd bf16 A-fragments ----
            short8 afrag[4];
#pragma unroll
            for (int kk = 0; kk < 4; ++kk) {
                int k0 = kk * 32 + kg * 8;
                uint32_t wa0 = (kk == 0) ? la.x : (kk == 1) ? la.z : (kk == 2) ? ha.x : ha.z;
                uint32_t wa1 = (kk == 0) ? la.y : (kk == 1) ? la.w : (kk == 2) ? ha.y : ha.w;
                uint32_t wb0 = (kk == 0) ? lb.x : (kk == 1) ? lb.z : (kk == 2) ? hb.x : hb.z;
                uint32_t wb1 = (kk == 0) ? lb.y : (kk == 1) ? lb.w : (kk == 2) ? hb.y : hb.w;
                float fa[8], fb[8];
                fp8_unpack8(wa0, wa1, fa);
                fp8_unpack8(wb0, wb1, fb);
                float xs[8];
#pragma unroll
                for (int j = 0; j < 8; ++j) {
                    xs[j] = fast_silu(fa[j] + fb[j] + attr * s_w1e[k0 + j]);
                }
                uint32_t* up = (uint32_t*)&afrag[kk];
                up[0] = cvt_pk_bf16(xs[0], xs[1]);
                up[1] = cvt_pk_bf16(xs[2], xs[3]);
                up[2] = cvt_pk_bf16(xs[4], xs[5]);
                up[3] = cvt_pk_bf16(xs[6], xs[7]);
            }

            // ---- layer 2 + fused silu + W3 dot (b2 folded into C) ----
            float pm0 = 0.f, pm1 = 0.f, pm2 = 0.f, pm3 = 0.f;
#pragma unroll
            for (int nt = 0; nt < 8; ++nt) {
                int n = nt * 16 + lrow;
                float b2v = s_b2[n];
                floatx4 acc = {b2v, b2v, b2v, b2v};
#pragma unroll
                for (int kk = 0; kk < 4; ++kk) {
                    const short8* bp = (const short8*)(w2t + (((nt * 4 + kk) * 64 + lane) << 3));
                    acc = __builtin_amdgcn_mfma_f32_16x16x32_bf16(afrag[kk], *bp, acc, 0, 0, 0);
                }
                float w3v = s_w3[n];
                pm0 += fast_silu(acc[0]) * w3v;
                pm1 += fast_silu(acc[1]) * w3v;
                pm2 += fast_silu(acc[2]) * w3v;
                pm3 += fast_silu(acc[3]) * w3v;
            }

            // rotate-reduce across the 16-lane row (DPP, pure VALU)
            REDUCE16(pm0);
            REDUCE16(pm1);
            REDUCE16(pm2);
            REDUCE16(pm3);
            // group kg holds m for edges ebase + kg*4 + {0..3} in pm0..pm3

            if (lrow < 12) {
                float mval = (rsel == 0) ? pm0 : (rsel == 1) ? pm1
                           : (rsel == 2) ? pm2 : pm3;
                float cd = half ? cd1 : cd0;
                float em = half ? em1 : em0;
                int rnode = half ? rn1 : rn0;
                float val = cd * mval * em;
                atomicAdd(&agg[rnode * 3 + dim], val);
            }
        }
        buf ^= 1;
    }
}

// ---------------------------------------------------------------------------
// Kernel 3: out = (coord + agg/100) * node_mask
// ---------------------------------------------------------------------------
__global__ __launch_bounds__(256) void finalize_kernel(
    const float* __restrict__ coord, const float* __restrict__ agg,
    const float* __restrict__ node_mask, float* __restrict__ out)
{
    int i = blockIdx.x * 256 + threadIdx.x;
    if (i < N_NODES * 3) {
        out[i] = (coord[i] + agg[i] * 0.01f) * node_mask[i / 3];
    }
}

extern "C" void kernel_launch(void* const* d_in, const int* in_sizes, int n_in,
                              void* d_out, int out_size, void* d_ws, size_t ws_size,
                              hipStream_t stream) {
    const float* h          = (const float*)d_in[0];
    const float* coord      = (const float*)d_in[1];
    const int*   eidx       = (const int*)d_in[2];   // [2][N_EDGES] int32
    const float* coord_diff = (const float*)d_in[3];
    const float* edge_attr  = (const float*)d_in[4];
    const float* node_mask  = (const float*)d_in[5];
    const float* edge_mask  = (const float*)d_in[6];
    const float* W1 = (const float*)d_in[7];
    const float* b1 = (const float*)d_in[8];
    const float* W2 = (const float*)d_in[9];
    const float* b2 = (const float*)d_in[10];
    const float* W3 = (const float*)d_in[11];
    float* out = (float*)d_out;

    uint8_t* At = (uint8_t*)d_ws;                          // 6.4 MB
    uint8_t* Bt = At + (size_t)N_NODES * 128;              // 6.4 MB
    float*  agg = (float*)(Bt + (size_t)N_NODES * 128);    // 600 KB

    hipMemsetAsync(agg, 0, N_NODES * 3 * sizeof(float), stream);

    precompute_AB<<<(N_NODES + 255) / 256, 256, 0, stream>>>(h, W1, b1, At, Bt);

    edge_kernel<<<512, 1024, 0, stream>>>(eidx, eidx + N_EDGES, edge_attr, edge_mask,
                                          coord_diff, W1, W2, b2, W3, At, Bt, agg);

    finalize_kernel<<<(N_NODES * 3 + 255) / 256, 256, 0, stream>>>(coord, agg, node_mask, out);
}

// Round 15
// 150.488 us; speedup vs baseline: 1.0620x; 1.0542x over previous
//
#include <hip/hip_runtime.h>
#include <hip/hip_bf16.h>
#include <stdint.h>

#define N_NODES 50000
#define N_EDGES 1000000
#define HIDDEN 128

using short8  = __attribute__((ext_vector_type(8))) short;
using floatx4 = __attribute__((ext_vector_type(4))) float;
using floatx2 = __attribute__((ext_vector_type(2))) float;

__device__ __forceinline__ float bf2f(uint16_t u) {
    return __uint_as_float(((uint32_t)u) << 16);
}
__device__ __forceinline__ uint16_t f2bf(float f) {
    uint32_t x = __float_as_uint(f);
    return (uint16_t)((x + 0x7FFFu + ((x >> 16) & 1u)) >> 16);
}
__device__ __forceinline__ uint32_t cvt_pk_bf16(float lo, float hi) {
    uint32_t r;
    asm("v_cvt_pk_bf16_f32 %0, %1, %2" : "=v"(r) : "v"(lo), "v"(hi));
    return r;
}
// single-trans silu: x*sigmoid(x), sigmoid(x)=0.5(1+tanh(x/2)),
// tanh(y)~=y*rsqrt(1+y^2). 1 trans op (rsq) vs exp+rcp (2 trans).
// max sigmoid err ~0.037 abs -> comparable to the fp8 noise already present.
__device__ __forceinline__ float fast_silu(float x) {
    float t = 0.5f * x;
    float r = __builtin_amdgcn_rsqf(fmaf(t, t, 1.0f));
    return fmaf(t * r, t, t);
}
// one f32 -> one fp8 e4m3 byte (gfx950 OCP format)
__device__ __forceinline__ uint8_t f2fp8(float v) {
    uint32_t p = __builtin_amdgcn_cvt_pk_fp8_f32(v, v, 0u, false);
    return (uint8_t)(p & 0xffu);
}
// unpack 8 fp8 bytes (two u32 words) -> 8 f32
__device__ __forceinline__ void fp8_unpack8(uint32_t w0, uint32_t w1, float f[8]) {
    floatx2 p;
    p = __builtin_amdgcn_cvt_pk_f32_fp8(w0, false); f[0] = p[0]; f[1] = p[1];
    p = __builtin_amdgcn_cvt_pk_f32_fp8(w0, true);  f[2] = p[0]; f[3] = p[1];
    p = __builtin_amdgcn_cvt_pk_f32_fp8(w1, false); f[4] = p[0]; f[5] = p[1];
    p = __builtin_amdgcn_cvt_pk_f32_fp8(w1, true);  f[6] = p[0]; f[7] = p[1];
}

// channel permutation for At/Bt storage: c = kk*32 + kg*8 + j  ->  kg*32 + kk*8 + j
__device__ __forceinline__ int perm_c(int c) {
    return ((c >> 3) & 3) * 32 + ((c >> 5) << 3) + (c & 7);
}

// DPP rotate-add within each 16-lane row (pure VALU, no LDS pipe)
template <int CTRL>
__device__ __forceinline__ float row_ror_add(float v) {
    return v + __int_as_float(__builtin_amdgcn_update_dpp(
        0, __float_as_int(v), CTRL, 0xf, 0xf, false));
}
#define REDUCE16(v)                  \
    v = row_ror_add<0x121>(v);       \
    v = row_ror_add<0x122>(v);       \
    v = row_ror_add<0x124>(v);       \
    v = row_ror_add<0x128>(v);

// ---------------------------------------------------------------------------
// Kernel 1: At[n][k] -> fp8, Bt[n][k] -> fp8 (perm_c channel order).
// NOTE: layer-1 output here is LINEAR (no silu) - silu happens in edge_kernel.
// ---------------------------------------------------------------------------
__global__ __launch_bounds__(256) void precompute_AB(
    const float* __restrict__ h, const float* __restrict__ W1,
    const float* __restrict__ b1,
    uint8_t* __restrict__ At, uint8_t* __restrict__ Bt)
{
    __shared__ uint16_t w1t[256 * 128];  // [c][j] bf16, XOR-swizzled, 64 KB
    int t = threadIdx.x;
    for (int idx = t; idx < 256 * 128; idx += 256) {
        int c = idx >> 7, j = idx & 127;
        float v = (c < 128) ? W1[j * 128 + c] : W1[(128 + j) * 128 + (c - 128)];
        int byte_off = (c << 8) + (j << 1);
        byte_off ^= ((c & 7) << 4);
        *(uint16_t*)((char*)w1t + byte_off) = f2bf(v);
    }
    __syncthreads();

    int wave = t >> 6, lane = t & 63;
    int lrow = lane & 15, kg = lane >> 4;

    for (int g = 0; g < 4; ++g) {
        int nodeBase = blockIdx.x * 256 + g * 64 + wave * 16;
        if (nodeBase >= N_NODES) break;
        int node = nodeBase + lrow;
        int nclamp = node < N_NODES ? node : N_NODES - 1;
        const float* hrow = h + (size_t)nclamp * 128;

        short8 afrag[4];
#pragma unroll
        for (int kk = 0; kk < 4; ++kk) {
            int k0 = kk * 32 + kg * 8;
            float4 f0 = *(const float4*)(hrow + k0);
            float4 f1 = *(const float4*)(hrow + k0 + 4);
            short8 a;
            uint32_t* ap = (uint32_t*)&a;
            ap[0] = cvt_pk_bf16(f0.x, f0.y);
            ap[1] = cvt_pk_bf16(f0.z, f0.w);
            ap[2] = cvt_pk_bf16(f1.x, f1.y);
            ap[3] = cvt_pk_bf16(f1.z, f1.w);
            afrag[kk] = a;
        }

        for (int nt = 0; nt < 16; ++nt) {
            floatx4 acc = {0.f, 0.f, 0.f, 0.f};
            int c = nt * 16 + lrow;
#pragma unroll
            for (int kk = 0; kk < 4; ++kk) {
                int byte_off = (c << 8) + ((kk * 32 + kg * 8) << 1);
                byte_off ^= ((c & 7) << 4);
                short8 b = *(const short8*)((const char*)w1t + byte_off);
                acc = __builtin_amdgcn_mfma_f32_16x16x32_bf16(afrag[kk], b, acc, 0, 0, 0);
            }
#pragma unroll
            for (int r = 0; r < 4; ++r) {
                int onode = nodeBase + kg * 4 + r;
                if (onode < N_NODES) {
                    float v = acc[r];
                    if (c < 128) {
                        At[(size_t)onode * 128 + perm_c(c)] = f2fp8(v + b1[c]);
                    } else {
                        int cc = c - 128;
                        Bt[(size_t)onode * 128 + perm_c(cc)] = f2fp8(v);
                    }
                }
            }
        }
    }
}

// ---------------------------------------------------------------------------
// Kernel 2: per-edge fused MLP (round-14 structure, single-trans silu).
// ---------------------------------------------------------------------------
__global__ __launch_bounds__(1024) void edge_kernel(
    const int* __restrict__ rowIdx, const int* __restrict__ colIdx,
    const float* __restrict__ edge_attr, const float* __restrict__ edge_mask,
    const float* __restrict__ coord_diff,
    const float* __restrict__ W1, const float* __restrict__ W2,
    const float* __restrict__ b2, const float* __restrict__ W3,
    const uint8_t* __restrict__ At, const uint8_t* __restrict__ Bt,
    float* __restrict__ agg)
{
    __shared__ uint16_t w2t[128 * 128];          // [nt][kk][lane][8] bf16, 32 KB
    __shared__ float s_w1e[128], s_b2[128], s_w3[128];
    __shared__ int s_idx[2][16][64];             // [buf][wave][0-31 row | 32-63 col], 8 KB
    int t = threadIdx.x;
    for (int idx = t; idx < 128 * 128; idx += 1024) {
        int j    = idx & 7;
        int ln   = (idx >> 3) & 63;
        int kkq  = (idx >> 9) & 3;
        int ntq  = idx >> 11;
        int n = ntq * 16 + (ln & 15);
        int k = kkq * 32 + (ln >> 4) * 8 + j;
        w2t[idx] = f2bf(W2[k * 128 + n]);
    }
    if (t < 128) { s_w1e[t] = W1[256 * 128 + t]; s_b2[t] = b2[t]; s_w3[t] = W3[t]; }
    __syncthreads();

    int wave = t >> 6, lane = t & 63;
    int lrow = lane & 15, kg = lane >> 4;

    const int numPairs = N_EDGES / 32;           // 31250
    int wavesTotal = gridDim.x * 16;
    int waveId = blockIdx.x * 16 + wave;
    if (waveId >= numPairs) return;

    // per-lane epilogue geometry (loop-invariant)
    int rsel = lrow / 3;                         // 0..5 (only 0..3 used)
    int dim  = lrow - rsel * 3;

    // ---- prologue: prefetch pair-0 indices into buf 0, wait once ----
    {
        int eb0 = waveId * 32;
        const int* gsrc = (lane < 32) ? (rowIdx + eb0 + lane)
                                      : (colIdx + eb0 + (lane & 31));
        __builtin_amdgcn_global_load_lds(
            (const __attribute__((address_space(1))) void*)gsrc,
            (__attribute__((address_space(3))) void*)&s_idx[0][wave][0], 4, 0, 0);
        __builtin_amdgcn_s_waitcnt(0x0F70);      // vmcnt(0)
    }

    int buf = 0;
    for (int pair = waveId; pair < numPairs; pair += wavesTotal) {
        // wait current buf's prefetch (skip the 2 in-flight atomics)
        __builtin_amdgcn_s_waitcnt(0x0F72);      // vmcnt(2)
        __builtin_amdgcn_sched_barrier(0);
        const int* mi = &s_idx[buf][wave][0];
        int r0 = mi[lrow],      c0 = mi[32 + lrow];
        int r1 = mi[16 + lrow], c1 = mi[48 + lrow];

        // prefetch next pair into the other buffer
        int nextp = pair + wavesTotal;
        if (nextp < numPairs) {
            int ebn = nextp * 32;
            const int* gsrc = (lane < 32) ? (rowIdx + ebn + lane)
                                          : (colIdx + ebn + (lane & 31));
            __builtin_amdgcn_global_load_lds(
                (const __attribute__((address_space(1))) void*)gsrc,
                (__attribute__((address_space(3))) void*)&s_idx[buf ^ 1][wave][0], 4, 0, 0);
        }

        int ebase0 = pair * 32;
        int ebase1 = ebase0 + 16;
        float attr0 = edge_attr[ebase0 + lrow];
        float attr1 = edge_attr[ebase1 + lrow];

        // ---- hoisted epilogue operands (all lanes, clamped; used if lrow<12) ----
        int sidx = kg * 4 + rsel;                        // 0..19; valid slot 0..15
        int eg0 = ebase0 + sidx;
        int eg1 = ebase1 + sidx;
        int eg0c = eg0 < N_EDGES - 1 ? eg0 : N_EDGES - 1;
        int eg1c = eg1 < N_EDGES - 1 ? eg1 : N_EDGES - 1;
        float cd0 = coord_diff[eg0c * 3 + dim];
        float em0 = edge_mask[eg0c];
        float cd1 = coord_diff[eg1c * 3 + dim];
        float em1 = edge_mask[eg1c];
        int sclamp = sidx < 16 ? sidx : 15;
        int rn0 = mi[sclamp];
        int rn1 = mi[16 + sclamp];

        // ---- all 8 gathers up front (half-0 first) ----
        const uint8_t* ar0 = At + (size_t)r0 * 128 + kg * 32;
        const uint8_t* br0 = Bt + (size_t)c0 * 128 + kg * 32;
        const uint8_t* ar1 = At + (size_t)r1 * 128 + kg * 32;
        const uint8_t* br1 = Bt + (size_t)c1 * 128 + kg * 32;
        uint4 la0 = *(const uint4*)(ar0);
        uint4 ha0 = *(const uint4*)(ar0 + 16);
        uint4 lb0 = *(const uint4*)(br0);
        uint4 hb0 = *(const uint4*)(br0 + 16);
        uint4 la1 = *(const uint4*)(ar1);
        uint4 ha1 = *(const uint4*)(ar1 + 16);
        uint4 lb1 = *(const uint4*)(br1);
        uint4 hb1 = *(const uint4*)(br1 + 16);

#pragma unroll
        for (int half = 0; half < 2; ++half) {
            float attr = half ? attr1 : attr0;
            uint4 la = half ? la1 : la0, ha = half ? ha1 : ha0;
            uint4 lb = half ? lb1 : lb0, hb = half ? hb1 : hb0;

            // ---- layer 1: fp8 rows -> silu'd bf16 A-fragments ----
            short8 afrag[4];
#pragma unroll
            for (int kk = 0; kk < 4; ++kk) {
                int k0 = kk * 32 + kg * 8;
                uint32_t wa0 = (kk == 0) ? la.x : (kk == 1) ? la.z : (kk == 2) ? ha.x : ha.z;
                uint32_t wa1 = (kk == 0) ? la.y : (kk == 1) ? la.w : (kk == 2) ? ha.y : ha.w;
                uint32_t wb0 = (kk == 0) ? lb.x : (kk == 1) ? lb.z : (kk == 2) ? hb.x : hb.z;
                uint32_t wb1 = (kk == 0) ? lb.y : (kk == 1) ? lb.w : (kk == 2) ? hb.y : hb.w;
                float fa[8], fb[8];
                fp8_unpack8(wa0, wa1, fa);
                fp8_unpack8(wb0, wb1, fb);
                float xs[8];
#pragma unroll
                for (int j = 0; j < 8; ++j) {
                    xs[j] = fast_silu(fa[j] + fb[j] + attr * s_w1e[k0 + j]);
                }
                uint32_t* up = (uint32_t*)&afrag[kk];
                up[0] = cvt_pk_bf16(xs[0], xs[1]);
                up[1] = cvt_pk_bf16(xs[2], xs[3]);
                up[2] = cvt_pk_bf16(xs[4], xs[5]);
                up[3] = cvt_pk_bf16(xs[6], xs[7]);
            }

            // ---- layer 2 + fused silu + W3 dot (b2 folded into C) ----
            float pm0 = 0.f, pm1 = 0.f, pm2 = 0.f, pm3 = 0.f;
#pragma unroll
            for (int nt = 0; nt < 8; ++nt) {
                int n = nt * 16 + lrow;
                float b2v = s_b2[n];
                floatx4 acc = {b2v, b2v, b2v, b2v};
#pragma unroll
                for (int kk = 0; kk < 4; ++kk) {
                    const short8* bp = (const short8*)(w2t + (((nt * 4 + kk) * 64 + lane) << 3));
                    acc = __builtin_amdgcn_mfma_f32_16x16x32_bf16(afrag[kk], *bp, acc, 0, 0, 0);
                }
                float w3v = s_w3[n];
                pm0 += fast_silu(acc[0]) * w3v;
                pm1 += fast_silu(acc[1]) * w3v;
                pm2 += fast_silu(acc[2]) * w3v;
                pm3 += fast_silu(acc[3]) * w3v;
            }

            // rotate-reduce across the 16-lane row (DPP, pure VALU)
            REDUCE16(pm0);
            REDUCE16(pm1);
            REDUCE16(pm2);
            REDUCE16(pm3);
            // group kg holds m for edges ebase + kg*4 + {0..3} in pm0..pm3

            if (lrow < 12) {
                float mval = (rsel == 0) ? pm0 : (rsel == 1) ? pm1
                           : (rsel == 2) ? pm2 : pm3;
                float cd = half ? cd1 : cd0;
                float em = half ? em1 : em0;
                int rnode = half ? rn1 : rn0;
                float val = cd * mval * em;
                atomicAdd(&agg[rnode * 3 + dim], val);
            }
        }
        buf ^= 1;
    }
}

// ---------------------------------------------------------------------------
// Kernel 3: out = (coord + agg/100) * node_mask
// ---------------------------------------------------------------------------
__global__ __launch_bounds__(256) void finalize_kernel(
    const float* __restrict__ coord, const float* __restrict__ agg,
    const float* __restrict__ node_mask, float* __restrict__ out)
{
    int i = blockIdx.x * 256 + threadIdx.x;
    if (i < N_NODES * 3) {
        out[i] = (coord[i] + agg[i] * 0.01f) * node_mask[i / 3];
    }
}

extern "C" void kernel_launch(void* const* d_in, const int* in_sizes, int n_in,
                              void* d_out, int out_size, void* d_ws, size_t ws_size,
                              hipStream_t stream) {
    const float* h          = (const float*)d_in[0];
    const float* coord      = (const float*)d_in[1];
    const int*   eidx       = (const int*)d_in[2];   // [2][N_EDGES] int32
    const float* coord_diff = (const float*)d_in[3];
    const float* edge_attr  = (const float*)d_in[4];
    const float* node_mask  = (const float*)d_in[5];
    const float* edge_mask  = (const float*)d_in[6];
    const float* W1 = (const float*)d_in[7];
    const float* b1 = (const float*)d_in[8];
    const float* W2 = (const float*)d_in[9];
    const float* b2 = (const float*)d_in[10];
    const float* W3 = (const float*)d_in[11];
    float* out = (float*)d_out;

    uint8_t* At = (uint8_t*)d_ws;                          // 6.4 MB
    uint8_t* Bt = At + (size_t)N_NODES * 128;              // 6.4 MB
    float*  agg = (float*)(Bt + (size_t)N_NODES * 128);    // 600 KB

    hipMemsetAsync(agg, 0, N_NODES * 3 * sizeof(float), stream);

    precompute_AB<<<(N_NODES + 255) / 256, 256, 0, stream>>>(h, W1, b1, At, Bt);

    edge_kernel<<<512, 1024, 0, stream>>>(eidx, eidx + N_EDGES, edge_attr, edge_mask,
                                          coord_diff, W1, W2, b2, W3, At, Bt, agg);

    finalize_kernel<<<(N_NODES * 3 + 255) / 256, 256, 0, stream>>>(coord, agg, node_mask, out);
}

// Round 16
// 149.273 us; speedup vs baseline: 1.0707x; 1.0081x over previous
//
#include <hip/hip_runtime.h>
#include <hip/hip_bf16.h>
#include <stdint.h>

#define N_NODES 50000
#define N_EDGES 1000000
#define HIDDEN 128

using short8  = __attribute__((ext_vector_type(8))) short;
using floatx4 = __attribute__((ext_vector_type(4))) float;
using floatx2 = __attribute__((ext_vector_type(2))) float;

__device__ __forceinline__ float bf2f(uint16_t u) {
    return __uint_as_float(((uint32_t)u) << 16);
}
__device__ __forceinline__ uint16_t f2bf(float f) {
    uint32_t x = __float_as_uint(f);
    return (uint16_t)((x + 0x7FFFu + ((x >> 16) & 1u)) >> 16);
}
__device__ __forceinline__ uint32_t cvt_pk_bf16(float lo, float hi) {
    uint32_t r;
    asm("v_cvt_pk_bf16_f32 %0, %1, %2" : "=v"(r) : "v"(lo), "v"(hi));
    return r;
}
// single-trans silu on a PAIR: packed ops (v_pk_mul/fma) for everything but
// the 2 rsq. sigmoid(x)=0.5(1+tanh(x/2)), tanh(y)~=y*rsqrt(1+y^2).
__device__ __forceinline__ floatx2 fast_silu2(floatx2 x) {
    floatx2 t = x * 0.5f;
    floatx2 s = t * t + 1.0f;
    floatx2 r;
    r[0] = __builtin_amdgcn_rsqf(s[0]);
    r[1] = __builtin_amdgcn_rsqf(s[1]);
    floatx2 u = t * r;
    return u * t + t;
}
// one f32 -> one fp8 e4m3 byte (gfx950 OCP format)
__device__ __forceinline__ uint8_t f2fp8(float v) {
    uint32_t p = __builtin_amdgcn_cvt_pk_fp8_f32(v, v, 0u, false);
    return (uint8_t)(p & 0xffu);
}

// channel permutation for At/Bt storage: c = kk*32 + kg*8 + j  ->  kg*32 + kk*8 + j
__device__ __forceinline__ int perm_c(int c) {
    return ((c >> 3) & 3) * 32 + ((c >> 5) << 3) + (c & 7);
}

// DPP rotate-add within each 16-lane row (pure VALU, no LDS pipe)
template <int CTRL>
__device__ __forceinline__ float row_ror_add(float v) {
    return v + __int_as_float(__builtin_amdgcn_update_dpp(
        0, __float_as_int(v), CTRL, 0xf, 0xf, false));
}
#define REDUCE16(v)                  \
    v = row_ror_add<0x121>(v);       \
    v = row_ror_add<0x122>(v);       \
    v = row_ror_add<0x124>(v);       \
    v = row_ror_add<0x128>(v);

// ---------------------------------------------------------------------------
// Kernel 1: At[n][k] -> fp8, Bt[n][k] -> fp8 (perm_c channel order).
// ---------------------------------------------------------------------------
__global__ __launch_bounds__(256) void precompute_AB(
    const float* __restrict__ h, const float* __restrict__ W1,
    const float* __restrict__ b1,
    uint8_t* __restrict__ At, uint8_t* __restrict__ Bt)
{
    __shared__ uint16_t w1t[256 * 128];  // [c][j] bf16, XOR-swizzled, 64 KB
    int t = threadIdx.x;
    for (int idx = t; idx < 256 * 128; idx += 256) {
        int c = idx >> 7, j = idx & 127;
        float v = (c < 128) ? W1[j * 128 + c] : W1[(128 + j) * 128 + (c - 128)];
        int byte_off = (c << 8) + (j << 1);
        byte_off ^= ((c & 7) << 4);
        *(uint16_t*)((char*)w1t + byte_off) = f2bf(v);
    }
    __syncthreads();

    int wave = t >> 6, lane = t & 63;
    int lrow = lane & 15, kg = lane >> 4;

    for (int g = 0; g < 4; ++g) {
        int nodeBase = blockIdx.x * 256 + g * 64 + wave * 16;
        if (nodeBase >= N_NODES) break;
        int node = nodeBase + lrow;
        int nclamp = node < N_NODES ? node : N_NODES - 1;
        const float* hrow = h + (size_t)nclamp * 128;

        short8 afrag[4];
#pragma unroll
        for (int kk = 0; kk < 4; ++kk) {
            int k0 = kk * 32 + kg * 8;
            float4 f0 = *(const float4*)(hrow + k0);
            float4 f1 = *(const float4*)(hrow + k0 + 4);
            short8 a;
            uint32_t* ap = (uint32_t*)&a;
            ap[0] = cvt_pk_bf16(f0.x, f0.y);
            ap[1] = cvt_pk_bf16(f0.z, f0.w);
            ap[2] = cvt_pk_bf16(f1.x, f1.y);
            ap[3] = cvt_pk_bf16(f1.z, f1.w);
            afrag[kk] = a;
        }

        for (int nt = 0; nt < 16; ++nt) {
            floatx4 acc = {0.f, 0.f, 0.f, 0.f};
            int c = nt * 16 + lrow;
#pragma unroll
            for (int kk = 0; kk < 4; ++kk) {
                int byte_off = (c << 8) + ((kk * 32 + kg * 8) << 1);
                byte_off ^= ((c & 7) << 4);
                short8 b = *(const short8*)((const char*)w1t + byte_off);
                acc = __builtin_amdgcn_mfma_f32_16x16x32_bf16(afrag[kk], b, acc, 0, 0, 0);
            }
#pragma unroll
            for (int r = 0; r < 4; ++r) {
                int onode = nodeBase + kg * 4 + r;
                if (onode < N_NODES) {
                    float v = acc[r];
                    if (c < 128) {
                        At[(size_t)onode * 128 + perm_c(c)] = f2fp8(v + b1[c]);
                    } else {
                        int cc = c - 128;
                        Bt[(size_t)onode * 128 + perm_c(cc)] = f2fp8(v);
                    }
                }
            }
        }
    }
}

// ---------------------------------------------------------------------------
// Kernel 2: per-edge fused MLP (round-15 structure) with PACKED fp32 math:
// layer-1 and epilogue arithmetic in floatx2 -> clang emits v_pk_add/mul/fma
// (2 values/inst); only the rsq trans ops stay scalar. ~25% fewer VALU inst.
// ---------------------------------------------------------------------------
__global__ __launch_bounds__(1024) void edge_kernel(
    const int* __restrict__ rowIdx, const int* __restrict__ colIdx,
    const float* __restrict__ edge_attr, const float* __restrict__ edge_mask,
    const float* __restrict__ coord_diff,
    const float* __restrict__ W1, const float* __restrict__ W2,
    const float* __restrict__ b2, const float* __restrict__ W3,
    const uint8_t* __restrict__ At, const uint8_t* __restrict__ Bt,
    float* __restrict__ agg)
{
    __shared__ uint16_t w2t[128 * 128];          // [nt][kk][lane][8] bf16, 32 KB
    __shared__ float s_w1e[128], s_b2[128], s_w3[128];
    __shared__ int s_idx[2][16][64];             // [buf][wave][0-31 row | 32-63 col], 8 KB
    int t = threadIdx.x;
    for (int idx = t; idx < 128 * 128; idx += 1024) {
        int j    = idx & 7;
        int ln   = (idx >> 3) & 63;
        int kkq  = (idx >> 9) & 3;
        int ntq  = idx >> 11;
        int n = ntq * 16 + (ln & 15);
        int k = kkq * 32 + (ln >> 4) * 8 + j;
        w2t[idx] = f2bf(W2[k * 128 + n]);
    }
    if (t < 128) { s_w1e[t] = W1[256 * 128 + t]; s_b2[t] = b2[t]; s_w3[t] = W3[t]; }
    __syncthreads();

    int wave = t >> 6, lane = t & 63;
    int lrow = lane & 15, kg = lane >> 4;

    const int numPairs = N_EDGES / 32;           // 31250
    int wavesTotal = gridDim.x * 16;
    int waveId = blockIdx.x * 16 + wave;
    if (waveId >= numPairs) return;

    // per-lane epilogue geometry (loop-invariant)
    int rsel = lrow / 3;                         // 0..5 (only 0..3 used)
    int dim  = lrow - rsel * 3;

    // ---- prologue: prefetch pair-0 indices into buf 0, wait once ----
    {
        int eb0 = waveId * 32;
        const int* gsrc = (lane < 32) ? (rowIdx + eb0 + lane)
                                      : (colIdx + eb0 + (lane & 31));
        __builtin_amdgcn_global_load_lds(
            (const __attribute__((address_space(1))) void*)gsrc,
            (__attribute__((address_space(3))) void*)&s_idx[0][wave][0], 4, 0, 0);
        __builtin_amdgcn_s_waitcnt(0x0F70);      // vmcnt(0)
    }

    int buf = 0;
    for (int pair = waveId; pair < numPairs; pair += wavesTotal) {
        // wait current buf's prefetch (skip the 2 in-flight atomics)
        __builtin_amdgcn_s_waitcnt(0x0F72);      // vmcnt(2)
        __builtin_amdgcn_sched_barrier(0);
        const int* mi = &s_idx[buf][wave][0];
        int r0 = mi[lrow],      c0 = mi[32 + lrow];
        int r1 = mi[16 + lrow], c1 = mi[48 + lrow];

        // prefetch next pair into the other buffer
        int nextp = pair + wavesTotal;
        if (nextp < numPairs) {
            int ebn = nextp * 32;
            const int* gsrc = (lane < 32) ? (rowIdx + ebn + lane)
                                          : (colIdx + ebn + (lane & 31));
            __builtin_amdgcn_global_load_lds(
                (const __attribute__((address_space(1))) void*)gsrc,
                (__attribute__((address_space(3))) void*)&s_idx[buf ^ 1][wave][0], 4, 0, 0);
        }

        int ebase0 = pair * 32;
        int ebase1 = ebase0 + 16;
        float attr0 = edge_attr[ebase0 + lrow];
        float attr1 = edge_attr[ebase1 + lrow];

        // ---- hoisted epilogue operands (all lanes, clamped; used if lrow<12) ----
        int sidx = kg * 4 + rsel;                        // 0..19; valid slot 0..15
        int eg0 = ebase0 + sidx;
        int eg1 = ebase1 + sidx;
        int eg0c = eg0 < N_EDGES - 1 ? eg0 : N_EDGES - 1;
        int eg1c = eg1 < N_EDGES - 1 ? eg1 : N_EDGES - 1;
        float cd0 = coord_diff[eg0c * 3 + dim];
        float em0 = edge_mask[eg0c];
        float cd1 = coord_diff[eg1c * 3 + dim];
        float em1 = edge_mask[eg1c];
        int sclamp = sidx < 16 ? sidx : 15;
        int rn0 = mi[sclamp];
        int rn1 = mi[16 + sclamp];

        // ---- all 8 gathers up front (half-0 first) ----
        const uint8_t* ar0 = At + (size_t)r0 * 128 + kg * 32;
        const uint8_t* br0 = Bt + (size_t)c0 * 128 + kg * 32;
        const uint8_t* ar1 = At + (size_t)r1 * 128 + kg * 32;
        const uint8_t* br1 = Bt + (size_t)c1 * 128 + kg * 32;
        uint4 la0 = *(const uint4*)(ar0);
        uint4 ha0 = *(const uint4*)(ar0 + 16);
        uint4 lb0 = *(const uint4*)(br0);
        uint4 hb0 = *(const uint4*)(br0 + 16);
        uint4 la1 = *(const uint4*)(ar1);
        uint4 ha1 = *(const uint4*)(ar1 + 16);
        uint4 lb1 = *(const uint4*)(br1);
        uint4 hb1 = *(const uint4*)(br1 + 16);

#pragma unroll
        for (int half = 0; half < 2; ++half) {
            float attr = half ? attr1 : attr0;
            uint4 la = half ? la1 : la0, ha = half ? ha1 : ha0;
            uint4 lb = half ? lb1 : lb0, hb = half ? hb1 : hb0;
            floatx2 attr2 = {attr, attr};

            // ---- layer 1: fp8 rows -> packed silu -> bf16 A-fragments ----
            short8 afrag[4];
#pragma unroll
            for (int kk = 0; kk < 4; ++kk) {
                int k0 = kk * 32 + kg * 8;
                uint32_t wa0 = (kk == 0) ? la.x : (kk == 1) ? la.z : (kk == 2) ? ha.x : ha.z;
                uint32_t wa1 = (kk == 0) ? la.y : (kk == 1) ? la.w : (kk == 2) ? ha.y : ha.w;
                uint32_t wb0 = (kk == 0) ? lb.x : (kk == 1) ? lb.z : (kk == 2) ? hb.x : hb.z;
                uint32_t wb1 = (kk == 0) ? lb.y : (kk == 1) ? lb.w : (kk == 2) ? hb.y : hb.w;
                floatx2 pa0 = __builtin_amdgcn_cvt_pk_f32_fp8(wa0, false);
                floatx2 pa1 = __builtin_amdgcn_cvt_pk_f32_fp8(wa0, true);
                floatx2 pa2 = __builtin_amdgcn_cvt_pk_f32_fp8(wa1, false);
                floatx2 pa3 = __builtin_amdgcn_cvt_pk_f32_fp8(wa1, true);
                floatx2 pb0 = __builtin_amdgcn_cvt_pk_f32_fp8(wb0, false);
                floatx2 pb1 = __builtin_amdgcn_cvt_pk_f32_fp8(wb0, true);
                floatx2 pb2 = __builtin_amdgcn_cvt_pk_f32_fp8(wb1, false);
                floatx2 pb3 = __builtin_amdgcn_cvt_pk_f32_fp8(wb1, true);
                const floatx2* wq = (const floatx2*)(&s_w1e[k0]);
                floatx2 y0 = fast_silu2(pa0 + pb0 + attr2 * wq[0]);
                floatx2 y1 = fast_silu2(pa1 + pb1 + attr2 * wq[1]);
                floatx2 y2 = fast_silu2(pa2 + pb2 + attr2 * wq[2]);
                floatx2 y3 = fast_silu2(pa3 + pb3 + attr2 * wq[3]);
                uint32_t* up = (uint32_t*)&afrag[kk];
                up[0] = cvt_pk_bf16(y0[0], y0[1]);
                up[1] = cvt_pk_bf16(y1[0], y1[1]);
                up[2] = cvt_pk_bf16(y2[0], y2[1]);
                up[3] = cvt_pk_bf16(y3[0], y3[1]);
            }

            // ---- layer 2 + packed silu + W3 dot (b2 folded into C) ----
            floatx2 pmA = {0.f, 0.f}, pmB = {0.f, 0.f};
#pragma unroll
            for (int nt = 0; nt < 8; ++nt) {
                int n = nt * 16 + lrow;
                float b2v = s_b2[n];
                floatx4 acc = {b2v, b2v, b2v, b2v};
#pragma unroll
                for (int kk = 0; kk < 4; ++kk) {
                    const short8* bp = (const short8*)(w2t + (((nt * 4 + kk) * 64 + lane) << 3));
                    acc = __builtin_amdgcn_mfma_f32_16x16x32_bf16(afrag[kk], *bp, acc, 0, 0, 0);
                }
                float w3v = s_w3[n];
                floatx2 w32 = {w3v, w3v};
                floatx2 a01 = {acc[0], acc[1]};
                floatx2 a23 = {acc[2], acc[3]};
                pmA += fast_silu2(a01) * w32;
                pmB += fast_silu2(a23) * w32;
            }
            float pm0 = pmA[0], pm1 = pmA[1], pm2 = pmB[0], pm3 = pmB[1];

            // rotate-reduce across the 16-lane row (DPP, pure VALU)
            REDUCE16(pm0);
            REDUCE16(pm1);
            REDUCE16(pm2);
            REDUCE16(pm3);
            // group kg holds m for edges ebase + kg*4 + {0..3} in pm0..pm3

            if (lrow < 12) {
                float mval = (rsel == 0) ? pm0 : (rsel == 1) ? pm1
                           : (rsel == 2) ? pm2 : pm3;
                float cd = half ? cd1 : cd0;
                float em = half ? em1 : em0;
                int rnode = half ? rn1 : rn0;
                float val = cd * mval * em;
                atomicAdd(&agg[rnode * 3 + dim], val);
            }
        }
        buf ^= 1;
    }
}

// ---------------------------------------------------------------------------
// Kernel 3: out = (coord + agg/100) * node_mask
// ---------------------------------------------------------------------------
__global__ __launch_bounds__(256) void finalize_kernel(
    const float* __restrict__ coord, const float* __restrict__ agg,
    const float* __restrict__ node_mask, float* __restrict__ out)
{
    int i = blockIdx.x * 256 + threadIdx.x;
    if (i < N_NODES * 3) {
        out[i] = (coord[i] + agg[i] * 0.01f) * node_mask[i / 3];
    }
}

extern "C" void kernel_launch(void* const* d_in, const int* in_sizes, int n_in,
                              void* d_out, int out_size, void* d_ws, size_t ws_size,
                              hipStream_t stream) {
    const float* h          = (const float*)d_in[0];
    const float* coord      = (const float*)d_in[1];
    const int*   eidx       = (const int*)d_in[2];   // [2][N_EDGES] int32
    const float* coord_diff = (const float*)d_in[3];
    const float* edge_attr  = (const float*)d_in[4];
    const float* node_mask  = (const float*)d_in[5];
    const float* edge_mask  = (const float*)d_in[6];
    const float* W1 = (const float*)d_in[7];
    const float* b1 = (const float*)d_in[8];
    const float* W2 = (const float*)d_in[9];
    const float* b2 = (const float*)d_in[10];
    const float* W3 = (const float*)d_in[11];
    float* out = (float*)d_out;

    uint8_t* At = (uint8_t*)d_ws;                          // 6.4 MB
    uint8_t* Bt = At + (size_t)N_NODES * 128;              // 6.4 MB
    float*  agg = (float*)(Bt + (size_t)N_NODES * 128);    // 600 KB

    hipMemsetAsync(agg, 0, N_NODES * 3 * sizeof(float), stream);

    precompute_AB<<<(N_NODES + 255) / 256, 256, 0, stream>>>(h, W1, b1, At, Bt);

    edge_kernel<<<512, 1024, 0, stream>>>(eidx, eidx + N_EDGES, edge_attr, edge_mask,
                                          coord_diff, W1, W2, b2, W3, At, Bt, agg);

    finalize_kernel<<<(N_NODES * 3 + 255) / 256, 256, 0, stream>>>(coord, agg, node_mask, out);
}

// Round 17
// 140.716 us; speedup vs baseline: 1.1358x; 1.0608x over previous
//
#include <hip/hip_runtime.h>
#include <hip/hip_bf16.h>
#include <stdint.h>

#define N_NODES 50000
#define N_EDGES 1000000
#define HIDDEN 128

using short8  = __attribute__((ext_vector_type(8))) short;
using floatx4 = __attribute__((ext_vector_type(4))) float;
using floatx2 = __attribute__((ext_vector_type(2))) float;

__device__ __forceinline__ float bf2f(uint16_t u) {
    return __uint_as_float(((uint32_t)u) << 16);
}
__device__ __forceinline__ uint16_t f2bf(float f) {
    uint32_t x = __float_as_uint(f);
    return (uint16_t)((x + 0x7FFFu + ((x >> 16) & 1u)) >> 16);
}
__device__ __forceinline__ uint32_t cvt_pk_bf16(float lo, float hi) {
    uint32_t r;
    asm("v_cvt_pk_bf16_f32 %0, %1, %2" : "=v"(r) : "v"(lo), "v"(hi));
    return r;
}
// single-trans silu on a PAIR: packed ops (v_pk_mul/fma) for everything but
// the 2 rsq. sigmoid(x)=0.5(1+tanh(x/2)), tanh(y)~=y*rsqrt(1+y^2).
__device__ __forceinline__ floatx2 fast_silu2(floatx2 x) {
    floatx2 t = x * 0.5f;
    floatx2 s = t * t + 1.0f;
    floatx2 r;
    r[0] = __builtin_amdgcn_rsqf(s[0]);
    r[1] = __builtin_amdgcn_rsqf(s[1]);
    floatx2 u = t * r;
    return u * t + t;
}
// one f32 -> one fp8 e4m3 byte (gfx950 OCP format)
__device__ __forceinline__ uint8_t f2fp8(float v) {
    uint32_t p = __builtin_amdgcn_cvt_pk_fp8_f32(v, v, 0u, false);
    return (uint8_t)(p & 0xffu);
}

// channel permutation for At/Bt storage: c = kk*32 + kg*8 + j  ->  kg*32 + kk*8 + j
__device__ __forceinline__ int perm_c(int c) {
    return ((c >> 3) & 3) * 32 + ((c >> 5) << 3) + (c & 7);
}

// DPP rotate-add within each 16-lane row (pure VALU, no LDS pipe)
template <int CTRL>
__device__ __forceinline__ float row_ror_add(float v) {
    return v + __int_as_float(__builtin_amdgcn_update_dpp(
        0, __float_as_int(v), CTRL, 0xf, 0xf, false));
}
#define REDUCE16(v)                  \
    v = row_ror_add<0x121>(v);       \
    v = row_ror_add<0x122>(v);       \
    v = row_ror_add<0x124>(v);       \
    v = row_ror_add<0x128>(v);

// ---------------------------------------------------------------------------
// Kernel 1: At[n][k] -> fp8, Bt[n][k] -> fp8 (perm_c channel order).
// W1 staging COALESCED: work item = (c, j-block of 8); lanes carry
// consecutive c so every global read is 64x4B contiguous; 8 bf16 packed in
// regs -> one 16B ds_write_b128 (old c-major mapping read at 512B lane
// stride = 64 transactions per instruction; staging dominated the kernel).
// ---------------------------------------------------------------------------
__global__ __launch_bounds__(256) void precompute_AB(
    const float* __restrict__ h, const float* __restrict__ W1,
    const float* __restrict__ b1,
    uint8_t* __restrict__ At, uint8_t* __restrict__ Bt)
{
    __shared__ uint16_t w1t[256 * 128];  // [c][j] bf16, XOR-swizzled, 64 KB
    int t = threadIdx.x;
    // 256 c x 16 j-blocks = 4096 items; 16 iters of 256 threads
    for (int item = t; item < 256 * 16; item += 256) {
        int c  = item & 255;
        int jb = item >> 8;              // j = jb*8 .. jb*8+7
        uint16_t vals[8];
#pragma unroll
        for (int jj = 0; jj < 8; ++jj) {
            int j = jb * 8 + jj;
            float v = (c < 128) ? W1[j * 128 + c]
                                : W1[(128 + j) * 128 + (c - 128)];
            vals[jj] = f2bf(v);
        }
        int byte_off = (c << 8) + (jb << 4);
        byte_off ^= ((c & 7) << 4);
        *(short8*)((char*)w1t + byte_off) = *(const short8*)vals;
    }
    __syncthreads();

    int wave = t >> 6, lane = t & 63;
    int lrow = lane & 15, kg = lane >> 4;

    for (int g = 0; g < 4; ++g) {
        int nodeBase = blockIdx.x * 256 + g * 64 + wave * 16;
        if (nodeBase >= N_NODES) break;
        int node = nodeBase + lrow;
        int nclamp = node < N_NODES ? node : N_NODES - 1;
        const float* hrow = h + (size_t)nclamp * 128;

        short8 afrag[4];
#pragma unroll
        for (int kk = 0; kk < 4; ++kk) {
            int k0 = kk * 32 + kg * 8;
            float4 f0 = *(const float4*)(hrow + k0);
            float4 f1 = *(const float4*)(hrow + k0 + 4);
            short8 a;
            uint32_t* ap = (uint32_t*)&a;
            ap[0] = cvt_pk_bf16(f0.x, f0.y);
            ap[1] = cvt_pk_bf16(f0.z, f0.w);
            ap[2] = cvt_pk_bf16(f1.x, f1.y);
            ap[3] = cvt_pk_bf16(f1.z, f1.w);
            afrag[kk] = a;
        }

        for (int nt = 0; nt < 16; ++nt) {
            floatx4 acc = {0.f, 0.f, 0.f, 0.f};
            int c = nt * 16 + lrow;
#pragma unroll
            for (int kk = 0; kk < 4; ++kk) {
                int byte_off = (c << 8) + ((kk * 32 + kg * 8) << 1);
                byte_off ^= ((c & 7) << 4);
                short8 b = *(const short8*)((const char*)w1t + byte_off);
                acc = __builtin_amdgcn_mfma_f32_16x16x32_bf16(afrag[kk], b, acc, 0, 0, 0);
            }
#pragma unroll
            for (int r = 0; r < 4; ++r) {
                int onode = nodeBase + kg * 4 + r;
                if (onode < N_NODES) {
                    float v = acc[r];
                    if (c < 128) {
                        At[(size_t)onode * 128 + perm_c(c)] = f2fp8(v + b1[c]);
                    } else {
                        int cc = c - 128;
                        Bt[(size_t)onode * 128 + perm_c(cc)] = f2fp8(v);
                    }
                }
            }
        }
    }
}

// ---------------------------------------------------------------------------
// Kernel 2: per-edge fused MLP (round-16 structure, packed fp32 math).
// UNCHANGED this round (control).
// ---------------------------------------------------------------------------
__global__ __launch_bounds__(1024) void edge_kernel(
    const int* __restrict__ rowIdx, const int* __restrict__ colIdx,
    const float* __restrict__ edge_attr, const float* __restrict__ edge_mask,
    const float* __restrict__ coord_diff,
    const float* __restrict__ W1, const float* __restrict__ W2,
    const float* __restrict__ b2, const float* __restrict__ W3,
    const uint8_t* __restrict__ At, const uint8_t* __restrict__ Bt,
    float* __restrict__ agg)
{
    __shared__ uint16_t w2t[128 * 128];          // [nt][kk][lane][8] bf16, 32 KB
    __shared__ float s_w1e[128], s_b2[128], s_w3[128];
    __shared__ int s_idx[2][16][64];             // [buf][wave][0-31 row | 32-63 col], 8 KB
    int t = threadIdx.x;
    for (int idx = t; idx < 128 * 128; idx += 1024) {
        int j    = idx & 7;
        int ln   = (idx >> 3) & 63;
        int kkq  = (idx >> 9) & 3;
        int ntq  = idx >> 11;
        int n = ntq * 16 + (ln & 15);
        int k = kkq * 32 + (ln >> 4) * 8 + j;
        w2t[idx] = f2bf(W2[k * 128 + n]);
    }
    if (t < 128) { s_w1e[t] = W1[256 * 128 + t]; s_b2[t] = b2[t]; s_w3[t] = W3[t]; }
    __syncthreads();

    int wave = t >> 6, lane = t & 63;
    int lrow = lane & 15, kg = lane >> 4;

    const int numPairs = N_EDGES / 32;           // 31250
    int wavesTotal = gridDim.x * 16;
    int waveId = blockIdx.x * 16 + wave;
    if (waveId >= numPairs) return;

    // per-lane epilogue geometry (loop-invariant)
    int rsel = lrow / 3;                         // 0..5 (only 0..3 used)
    int dim  = lrow - rsel * 3;

    // ---- prologue: prefetch pair-0 indices into buf 0, wait once ----
    {
        int eb0 = waveId * 32;
        const int* gsrc = (lane < 32) ? (rowIdx + eb0 + lane)
                                      : (colIdx + eb0 + (lane & 31));
        __builtin_amdgcn_global_load_lds(
            (const __attribute__((address_space(1))) void*)gsrc,
            (__attribute__((address_space(3))) void*)&s_idx[0][wave][0], 4, 0, 0);
        __builtin_amdgcn_s_waitcnt(0x0F70);      // vmcnt(0)
    }

    int buf = 0;
    for (int pair = waveId; pair < numPairs; pair += wavesTotal) {
        // wait current buf's prefetch (skip the 2 in-flight atomics)
        __builtin_amdgcn_s_waitcnt(0x0F72);      // vmcnt(2)
        __builtin_amdgcn_sched_barrier(0);
        const int* mi = &s_idx[buf][wave][0];
        int r0 = mi[lrow],      c0 = mi[32 + lrow];
        int r1 = mi[16 + lrow], c1 = mi[48 + lrow];

        // prefetch next pair into the other buffer
        int nextp = pair + wavesTotal;
        if (nextp < numPairs) {
            int ebn = nextp * 32;
            const int* gsrc = (lane < 32) ? (rowIdx + ebn + lane)
                                          : (colIdx + ebn + (lane & 31));
            __builtin_amdgcn_global_load_lds(
                (const __attribute__((address_space(1))) void*)gsrc,
                (__attribute__((address_space(3))) void*)&s_idx[buf ^ 1][wave][0], 4, 0, 0);
        }

        int ebase0 = pair * 32;
        int ebase1 = ebase0 + 16;
        float attr0 = edge_attr[ebase0 + lrow];
        float attr1 = edge_attr[ebase1 + lrow];

        // ---- hoisted epilogue operands (all lanes, clamped; used if lrow<12) ----
        int sidx = kg * 4 + rsel;                        // 0..19; valid slot 0..15
        int eg0 = ebase0 + sidx;
        int eg1 = ebase1 + sidx;
        int eg0c = eg0 < N_EDGES - 1 ? eg0 : N_EDGES - 1;
        int eg1c = eg1 < N_EDGES - 1 ? eg1 : N_EDGES - 1;
        float cd0 = coord_diff[eg0c * 3 + dim];
        float em0 = edge_mask[eg0c];
        float cd1 = coord_diff[eg1c * 3 + dim];
        float em1 = edge_mask[eg1c];
        int sclamp = sidx < 16 ? sidx : 15;
        int rn0 = mi[sclamp];
        int rn1 = mi[16 + sclamp];

        // ---- all 8 gathers up front (half-0 first) ----
        const uint8_t* ar0 = At + (size_t)r0 * 128 + kg * 32;
        const uint8_t* br0 = Bt + (size_t)c0 * 128 + kg * 32;
        const uint8_t* ar1 = At + (size_t)r1 * 128 + kg * 32;
        const uint8_t* br1 = Bt + (size_t)c1 * 128 + kg * 32;
        uint4 la0 = *(const uint4*)(ar0);
        uint4 ha0 = *(const uint4*)(ar0 + 16);
        uint4 lb0 = *(const uint4*)(br0);
        uint4 hb0 = *(const uint4*)(br0 + 16);
        uint4 la1 = *(const uint4*)(ar1);
        uint4 ha1 = *(const uint4*)(ar1 + 16);
        uint4 lb1 = *(const uint4*)(br1);
        uint4 hb1 = *(const uint4*)(br1 + 16);

#pragma unroll
        for (int half = 0; half < 2; ++half) {
            float attr = half ? attr1 : attr0;
            uint4 la = half ? la1 : la0, ha = half ? ha1 : ha0;
            uint4 lb = half ? lb1 : lb0, hb = half ? hb1 : hb0;
            floatx2 attr2 = {attr, attr};

            // ---- layer 1: fp8 rows -> packed silu -> bf16 A-fragments ----
            short8 afrag[4];
#pragma unroll
            for (int kk = 0; kk < 4; ++kk) {
                int k0 = kk * 32 + kg * 8;
                uint32_t wa0 = (kk == 0) ? la.x : (kk == 1) ? la.z : (kk == 2) ? ha.x : ha.z;
                uint32_t wa1 = (kk == 0) ? la.y : (kk == 1) ? la.w : (kk == 2) ? ha.y : ha.w;
                uint32_t wb0 = (kk == 0) ? lb.x : (kk == 1) ? lb.z : (kk == 2) ? hb.x : hb.z;
                uint32_t wb1 = (kk == 0) ? lb.y : (kk == 1) ? lb.w : (kk == 2) ? hb.y : hb.w;
                floatx2 pa0 = __builtin_amdgcn_cvt_pk_f32_fp8(wa0, false);
                floatx2 pa1 = __builtin_amdgcn_cvt_pk_f32_fp8(wa0, true);
                floatx2 pa2 = __builtin_amdgcn_cvt_pk_f32_fp8(wa1, false);
                floatx2 pa3 = __builtin_amdgcn_cvt_pk_f32_fp8(wa1, true);
                floatx2 pb0 = __builtin_amdgcn_cvt_pk_f32_fp8(wb0, false);
                floatx2 pb1 = __builtin_amdgcn_cvt_pk_f32_fp8(wb0, true);
                floatx2 pb2 = __builtin_amdgcn_cvt_pk_f32_fp8(wb1, false);
                floatx2 pb3 = __builtin_amdgcn_cvt_pk_f32_fp8(wb1, true);
                const floatx2* wq = (const floatx2*)(&s_w1e[k0]);
                floatx2 y0 = fast_silu2(pa0 + pb0 + attr2 * wq[0]);
                floatx2 y1 = fast_silu2(pa1 + pb1 + attr2 * wq[1]);
                floatx2 y2 = fast_silu2(pa2 + pb2 + attr2 * wq[2]);
                floatx2 y3 = fast_silu2(pa3 + pb3 + attr2 * wq[3]);
                uint32_t* up = (uint32_t*)&afrag[kk];
                up[0] = cvt_pk_bf16(y0[0], y0[1]);
                up[1] = cvt_pk_bf16(y1[0], y1[1]);
                up[2] = cvt_pk_bf16(y2[0], y2[1]);
                up[3] = cvt_pk_bf16(y3[0], y3[1]);
            }

            // ---- layer 2 + packed silu + W3 dot (b2 folded into C) ----
            floatx2 pmA = {0.f, 0.f}, pmB = {0.f, 0.f};
#pragma unroll
            for (int nt = 0; nt < 8; ++nt) {
                int n = nt * 16 + lrow;
                float b2v = s_b2[n];
                floatx4 acc = {b2v, b2v, b2v, b2v};
#pragma unroll
                for (int kk = 0; kk < 4; ++kk) {
                    const short8* bp = (const short8*)(w2t + (((nt * 4 + kk) * 64 + lane) << 3));
                    acc = __builtin_amdgcn_mfma_f32_16x16x32_bf16(afrag[kk], *bp, acc, 0, 0, 0);
                }
                float w3v = s_w3[n];
                floatx2 w32 = {w3v, w3v};
                floatx2 a01 = {acc[0], acc[1]};
                floatx2 a23 = {acc[2], acc[3]};
                pmA += fast_silu2(a01) * w32;
                pmB += fast_silu2(a23) * w32;
            }
            float pm0 = pmA[0], pm1 = pmA[1], pm2 = pmB[0], pm3 = pmB[1];

            // rotate-reduce across the 16-lane row (DPP, pure VALU)
            REDUCE16(pm0);
            REDUCE16(pm1);
            REDUCE16(pm2);
            REDUCE16(pm3);
            // group kg holds m for edges ebase + kg*4 + {0..3} in pm0..pm3

            if (lrow < 12) {
                float mval = (rsel == 0) ? pm0 : (rsel == 1) ? pm1
                           : (rsel == 2) ? pm2 : pm3;
                float cd = half ? cd1 : cd0;
                float em = half ? em1 : em0;
                int rnode = half ? rn1 : rn0;
                float val = cd * mval * em;
                atomicAdd(&agg[rnode * 3 + dim], val);
            }
        }
        buf ^= 1;
    }
}

// ---------------------------------------------------------------------------
// Kernel 3: out = (coord + agg/100) * node_mask
// ---------------------------------------------------------------------------
__global__ __launch_bounds__(256) void finalize_kernel(
    const float* __restrict__ coord, const float* __restrict__ agg,
    const float* __restrict__ node_mask, float* __restrict__ out)
{
    int i = blockIdx.x * 256 + threadIdx.x;
    if (i < N_NODES * 3) {
        out[i] = (coord[i] + agg[i] * 0.01f) * node_mask[i / 3];
    }
}

extern "C" void kernel_launch(void* const* d_in, const int* in_sizes, int n_in,
                              void* d_out, int out_size, void* d_ws, size_t ws_size,
                              hipStream_t stream) {
    const float* h          = (const float*)d_in[0];
    const float* coord      = (const float*)d_in[1];
    const int*   eidx       = (const int*)d_in[2];   // [2][N_EDGES] int32
    const float* coord_diff = (const float*)d_in[3];
    const float* edge_attr  = (const float*)d_in[4];
    const float* node_mask  = (const float*)d_in[5];
    const float* edge_mask  = (const float*)d_in[6];
    const float* W1 = (const float*)d_in[7];
    const float* b1 = (const float*)d_in[8];
    const float* W2 = (const float*)d_in[9];
    const float* b2 = (const float*)d_in[10];
    const float* W3 = (const float*)d_in[11];
    float* out = (float*)d_out;

    uint8_t* At = (uint8_t*)d_ws;                          // 6.4 MB
    uint8_t* Bt = At + (size_t)N_NODES * 128;              // 6.4 MB
    float*  agg = (float*)(Bt + (size_t)N_NODES * 128);    // 600 KB

    hipMemsetAsync(agg, 0, N_NODES * 3 * sizeof(float), stream);

    precompute_AB<<<(N_NODES + 255) / 256, 256, 0, stream>>>(h, W1, b1, At, Bt);

    edge_kernel<<<512, 1024, 0, stream>>>(eidx, eidx + N_EDGES, edge_attr, edge_mask,
                                          coord_diff, W1, W2, b2, W3, At, Bt, agg);

    finalize_kernel<<<(N_NODES * 3 + 255) / 256, 256, 0, stream>>>(coord, agg, node_mask, out);
}

// Round 18
// 119.811 us; speedup vs baseline: 1.3339x; 1.1745x over previous
//
#include <hip/hip_runtime.h>
#include <hip/hip_bf16.h>
#include <stdint.h>

#define N_NODES 50000
#define N_EDGES 1000000
#define HIDDEN 128

using short8  = __attribute__((ext_vector_type(8))) short;
using floatx4 = __attribute__((ext_vector_type(4))) float;
using floatx2 = __attribute__((ext_vector_type(2))) float;

__device__ __forceinline__ float bf2f(uint16_t u) {
    return __uint_as_float(((uint32_t)u) << 16);
}
__device__ __forceinline__ uint16_t f2bf(float f) {
    uint32_t x = __float_as_uint(f);
    return (uint16_t)((x + 0x7FFFu + ((x >> 16) & 1u)) >> 16);
}
__device__ __forceinline__ uint32_t cvt_pk_bf16(float lo, float hi) {
    uint32_t r;
    asm("v_cvt_pk_bf16_f32 %0, %1, %2" : "=v"(r) : "v"(lo), "v"(hi));
    return r;
}
// single-trans silu on a PAIR: packed ops (v_pk_mul/fma) for everything but
// the 2 rsq. sigmoid(x)=0.5(1+tanh(x/2)), tanh(y)~=y*rsqrt(1+y^2).
__device__ __forceinline__ floatx2 fast_silu2(floatx2 x) {
    floatx2 t = x * 0.5f;
    floatx2 s = t * t + 1.0f;
    floatx2 r;
    r[0] = __builtin_amdgcn_rsqf(s[0]);
    r[1] = __builtin_amdgcn_rsqf(s[1]);
    floatx2 u = t * r;
    return u * t + t;
}
// one f32 -> one fp8 e4m3 byte (gfx950 OCP format)
__device__ __forceinline__ uint8_t f2fp8(float v) {
    uint32_t p = __builtin_amdgcn_cvt_pk_fp8_f32(v, v, 0u, false);
    return (uint8_t)(p & 0xffu);
}

// channel permutation for At/Bt storage: c = kk*32 + kg*8 + j  ->  kg*32 + kk*8 + j
__device__ __forceinline__ int perm_c(int c) {
    return ((c >> 3) & 3) * 32 + ((c >> 5) << 3) + (c & 7);
}

// DPP rotate-add within each 16-lane row (pure VALU, no LDS pipe)
template <int CTRL>
__device__ __forceinline__ float row_ror_add(float v) {
    return v + __int_as_float(__builtin_amdgcn_update_dpp(
        0, __float_as_int(v), CTRL, 0xf, 0xf, false));
}
#define REDUCE16(v)                  \
    v = row_ror_add<0x121>(v);       \
    v = row_ror_add<0x122>(v);       \
    v = row_ror_add<0x124>(v);       \
    v = row_ror_add<0x128>(v);

// ---------------------------------------------------------------------------
// Kernel 1: At[n][k] -> fp8, Bt[n][k] -> fp8 (perm_c channel order).
// Output now staged per-wave in LDS (16 nodes x 256 cols fp8 = 4KB) and
// stored with 16B/lane fully-coalesced runs (lanes 0-7 = the node's whole
// 128B At row, lanes 8-15 = Bt row). The old path stored scattered SINGLE
// BYTES (1B/lane at 128B+ stride) - dozens of transactions per instruction.
// Also zeroes agg (memset dispatch folded in).
// ---------------------------------------------------------------------------
__global__ __launch_bounds__(256) void precompute_AB(
    const float* __restrict__ h, const float* __restrict__ W1,
    const float* __restrict__ b1,
    uint8_t* __restrict__ At, uint8_t* __restrict__ Bt,
    float* __restrict__ agg)
{
    __shared__ uint16_t w1t[256 * 128];      // [c][j] bf16, XOR-swizzled, 64 KB
    __shared__ uint8_t s_out[4][16][256];    // [wave][node_local][col], 16 KB
    int t = threadIdx.x;

    // zero agg (was a separate hipMemsetAsync dispatch)
    for (int i = blockIdx.x * 256 + t; i < N_NODES * 3; i += gridDim.x * 256)
        agg[i] = 0.0f;

    // coalesced W1 staging: lanes carry consecutive c; one 16B ds_write each
    for (int item = t; item < 256 * 16; item += 256) {
        int c  = item & 255;
        int jb = item >> 8;              // j = jb*8 .. jb*8+7
        uint16_t vals[8];
#pragma unroll
        for (int jj = 0; jj < 8; ++jj) {
            int j = jb * 8 + jj;
            float v = (c < 128) ? W1[j * 128 + c]
                                : W1[(128 + j) * 128 + (c - 128)];
            vals[jj] = f2bf(v);
        }
        int byte_off = (c << 8) + (jb << 4);
        byte_off ^= ((c & 7) << 4);
        *(short8*)((char*)w1t + byte_off) = *(const short8*)vals;
    }
    __syncthreads();

    int wave = t >> 6, lane = t & 63;
    int lrow = lane & 15, kg = lane >> 4;

    for (int g = 0; g < 4; ++g) {
        int nodeBase = blockIdx.x * 256 + g * 64 + wave * 16;
        if (nodeBase >= N_NODES) break;
        int node = nodeBase + lrow;
        int nclamp = node < N_NODES ? node : N_NODES - 1;
        const float* hrow = h + (size_t)nclamp * 128;

        short8 afrag[4];
#pragma unroll
        for (int kk = 0; kk < 4; ++kk) {
            int k0 = kk * 32 + kg * 8;
            float4 f0 = *(const float4*)(hrow + k0);
            float4 f1 = *(const float4*)(hrow + k0 + 4);
            short8 a;
            uint32_t* ap = (uint32_t*)&a;
            ap[0] = cvt_pk_bf16(f0.x, f0.y);
            ap[1] = cvt_pk_bf16(f0.z, f0.w);
            ap[2] = cvt_pk_bf16(f1.x, f1.y);
            ap[3] = cvt_pk_bf16(f1.z, f1.w);
            afrag[kk] = a;
        }

        for (int nt = 0; nt < 16; ++nt) {
            floatx4 acc = {0.f, 0.f, 0.f, 0.f};
            int c = nt * 16 + lrow;
#pragma unroll
            for (int kk = 0; kk < 4; ++kk) {
                int byte_off = (c << 8) + ((kk * 32 + kg * 8) << 1);
                byte_off ^= ((c & 7) << 4);
                short8 b = *(const short8*)((const char*)w1t + byte_off);
                acc = __builtin_amdgcn_mfma_f32_16x16x32_bf16(afrag[kk], b, acc, 0, 0, 0);
            }
#pragma unroll
            for (int r = 0; r < 4; ++r) {
                int nl = kg * 4 + r;
                float v = acc[r];
                if (c < 128) {
                    s_out[wave][nl][perm_c(c)] = f2fp8(v + b1[c]);
                } else {
                    s_out[wave][nl][128 + perm_c(c - 128)] = f2fp8(v);
                }
            }
        }

        // wave-local coalesced store: 16 nodes x 256B; lanes 0-7 cover the
        // node's At row (128B), lanes 8-15 the Bt row.
#pragma unroll
        for (int it = 0; it < 4; ++it) {
            int nl = it * 4 + kg;            // node_local 0..15
            int colb = lrow * 16;            // 16B chunk within the 256 cols
            int onode = nodeBase + nl;
            if (onode < N_NODES) {
                uint4 v4 = *(const uint4*)&s_out[wave][nl][colb];
                if (colb < 128)
                    *(uint4*)(At + (size_t)onode * 128 + colb) = v4;
                else
                    *(uint4*)(Bt + (size_t)onode * 128 + (colb - 128)) = v4;
            }
        }
    }
}

// ---------------------------------------------------------------------------
// Kernel 2: per-edge fused MLP (round-16 structure, packed fp32 math).
// UNCHANGED (control).
// ---------------------------------------------------------------------------
__global__ __launch_bounds__(1024) void edge_kernel(
    const int* __restrict__ rowIdx, const int* __restrict__ colIdx,
    const float* __restrict__ edge_attr, const float* __restrict__ edge_mask,
    const float* __restrict__ coord_diff,
    const float* __restrict__ W1, const float* __restrict__ W2,
    const float* __restrict__ b2, const float* __restrict__ W3,
    const uint8_t* __restrict__ At, const uint8_t* __restrict__ Bt,
    float* __restrict__ agg)
{
    __shared__ uint16_t w2t[128 * 128];          // [nt][kk][lane][8] bf16, 32 KB
    __shared__ float s_w1e[128], s_b2[128], s_w3[128];
    __shared__ int s_idx[2][16][64];             // [buf][wave][0-31 row | 32-63 col], 8 KB
    int t = threadIdx.x;
    for (int idx = t; idx < 128 * 128; idx += 1024) {
        int j    = idx & 7;
        int ln   = (idx >> 3) & 63;
        int kkq  = (idx >> 9) & 3;
        int ntq  = idx >> 11;
        int n = ntq * 16 + (ln & 15);
        int k = kkq * 32 + (ln >> 4) * 8 + j;
        w2t[idx] = f2bf(W2[k * 128 + n]);
    }
    if (t < 128) { s_w1e[t] = W1[256 * 128 + t]; s_b2[t] = b2[t]; s_w3[t] = W3[t]; }
    __syncthreads();

    int wave = t >> 6, lane = t & 63;
    int lrow = lane & 15, kg = lane >> 4;

    const int numPairs = N_EDGES / 32;           // 31250
    int wavesTotal = gridDim.x * 16;
    int waveId = blockIdx.x * 16 + wave;
    if (waveId >= numPairs) return;

    // per-lane epilogue geometry (loop-invariant)
    int rsel = lrow / 3;                         // 0..5 (only 0..3 used)
    int dim  = lrow - rsel * 3;

    // ---- prologue: prefetch pair-0 indices into buf 0, wait once ----
    {
        int eb0 = waveId * 32;
        const int* gsrc = (lane < 32) ? (rowIdx + eb0 + lane)
                                      : (colIdx + eb0 + (lane & 31));
        __builtin_amdgcn_global_load_lds(
            (const __attribute__((address_space(1))) void*)gsrc,
            (__attribute__((address_space(3))) void*)&s_idx[0][wave][0], 4, 0, 0);
        __builtin_amdgcn_s_waitcnt(0x0F70);      // vmcnt(0)
    }

    int buf = 0;
    for (int pair = waveId; pair < numPairs; pair += wavesTotal) {
        // wait current buf's prefetch (skip the 2 in-flight atomics)
        __builtin_amdgcn_s_waitcnt(0x0F72);      // vmcnt(2)
        __builtin_amdgcn_sched_barrier(0);
        const int* mi = &s_idx[buf][wave][0];
        int r0 = mi[lrow],      c0 = mi[32 + lrow];
        int r1 = mi[16 + lrow], c1 = mi[48 + lrow];

        // prefetch next pair into the other buffer
        int nextp = pair + wavesTotal;
        if (nextp < numPairs) {
            int ebn = nextp * 32;
            const int* gsrc = (lane < 32) ? (rowIdx + ebn + lane)
                                          : (colIdx + ebn + (lane & 31));
            __builtin_amdgcn_global_load_lds(
                (const __attribute__((address_space(1))) void*)gsrc,
                (__attribute__((address_space(3))) void*)&s_idx[buf ^ 1][wave][0], 4, 0, 0);
        }

        int ebase0 = pair * 32;
        int ebase1 = ebase0 + 16;
        float attr0 = edge_attr[ebase0 + lrow];
        float attr1 = edge_attr[ebase1 + lrow];

        // ---- hoisted epilogue operands (all lanes, clamped; used if lrow<12) ----
        int sidx = kg * 4 + rsel;                        // 0..19; valid slot 0..15
        int eg0 = ebase0 + sidx;
        int eg1 = ebase1 + sidx;
        int eg0c = eg0 < N_EDGES - 1 ? eg0 : N_EDGES - 1;
        int eg1c = eg1 < N_EDGES - 1 ? eg1 : N_EDGES - 1;
        float cd0 = coord_diff[eg0c * 3 + dim];
        float em0 = edge_mask[eg0c];
        float cd1 = coord_diff[eg1c * 3 + dim];
        float em1 = edge_mask[eg1c];
        int sclamp = sidx < 16 ? sidx : 15;
        int rn0 = mi[sclamp];
        int rn1 = mi[16 + sclamp];

        // ---- all 8 gathers up front (half-0 first) ----
        const uint8_t* ar0 = At + (size_t)r0 * 128 + kg * 32;
        const uint8_t* br0 = Bt + (size_t)c0 * 128 + kg * 32;
        const uint8_t* ar1 = At + (size_t)r1 * 128 + kg * 32;
        const uint8_t* br1 = Bt + (size_t)c1 * 128 + kg * 32;
        uint4 la0 = *(const uint4*)(ar0);
        uint4 ha0 = *(const uint4*)(ar0 + 16);
        uint4 lb0 = *(const uint4*)(br0);
        uint4 hb0 = *(const uint4*)(br0 + 16);
        uint4 la1 = *(const uint4*)(ar1);
        uint4 ha1 = *(const uint4*)(ar1 + 16);
        uint4 lb1 = *(const uint4*)(br1);
        uint4 hb1 = *(const uint4*)(br1 + 16);

#pragma unroll
        for (int half = 0; half < 2; ++half) {
            float attr = half ? attr1 : attr0;
            uint4 la = half ? la1 : la0, ha = half ? ha1 : ha0;
            uint4 lb = half ? lb1 : lb0, hb = half ? hb1 : hb0;
            floatx2 attr2 = {attr, attr};

            // ---- layer 1: fp8 rows -> packed silu -> bf16 A-fragments ----
            short8 afrag[4];
#pragma unroll
            for (int kk = 0; kk < 4; ++kk) {
                int k0 = kk * 32 + kg * 8;
                uint32_t wa0 = (kk == 0) ? la.x : (kk == 1) ? la.z : (kk == 2) ? ha.x : ha.z;
                uint32_t wa1 = (kk == 0) ? la.y : (kk == 1) ? la.w : (kk == 2) ? ha.y : ha.w;
                uint32_t wb0 = (kk == 0) ? lb.x : (kk == 1) ? lb.z : (kk == 2) ? hb.x : hb.z;
                uint32_t wb1 = (kk == 0) ? lb.y : (kk == 1) ? lb.w : (kk == 2) ? hb.y : hb.w;
                floatx2 pa0 = __builtin_amdgcn_cvt_pk_f32_fp8(wa0, false);
                floatx2 pa1 = __builtin_amdgcn_cvt_pk_f32_fp8(wa0, true);
                floatx2 pa2 = __builtin_amdgcn_cvt_pk_f32_fp8(wa1, false);
                floatx2 pa3 = __builtin_amdgcn_cvt_pk_f32_fp8(wa1, true);
                floatx2 pb0 = __builtin_amdgcn_cvt_pk_f32_fp8(wb0, false);
                floatx2 pb1 = __builtin_amdgcn_cvt_pk_f32_fp8(wb0, true);
                floatx2 pb2 = __builtin_amdgcn_cvt_pk_f32_fp8(wb1, false);
                floatx2 pb3 = __builtin_amdgcn_cvt_pk_f32_fp8(wb1, true);
                const floatx2* wq = (const floatx2*)(&s_w1e[k0]);
                floatx2 y0 = fast_silu2(pa0 + pb0 + attr2 * wq[0]);
                floatx2 y1 = fast_silu2(pa1 + pb1 + attr2 * wq[1]);
                floatx2 y2 = fast_silu2(pa2 + pb2 + attr2 * wq[2]);
                floatx2 y3 = fast_silu2(pa3 + pb3 + attr2 * wq[3]);
                uint32_t* up = (uint32_t*)&afrag[kk];
                up[0] = cvt_pk_bf16(y0[0], y0[1]);
                up[1] = cvt_pk_bf16(y1[0], y1[1]);
                up[2] = cvt_pk_bf16(y2[0], y2[1]);
                up[3] = cvt_pk_bf16(y3[0], y3[1]);
            }

            // ---- layer 2 + packed silu + W3 dot (b2 folded into C) ----
            floatx2 pmA = {0.f, 0.f}, pmB = {0.f, 0.f};
#pragma unroll
            for (int nt = 0; nt < 8; ++nt) {
                int n = nt * 16 + lrow;
                float b2v = s_b2[n];
                floatx4 acc = {b2v, b2v, b2v, b2v};
#pragma unroll
                for (int kk = 0; kk < 4; ++kk) {
                    const short8* bp = (const short8*)(w2t + (((nt * 4 + kk) * 64 + lane) << 3));
                    acc = __builtin_amdgcn_mfma_f32_16x16x32_bf16(afrag[kk], *bp, acc, 0, 0, 0);
                }
                float w3v = s_w3[n];
                floatx2 w32 = {w3v, w3v};
                floatx2 a01 = {acc[0], acc[1]};
                floatx2 a23 = {acc[2], acc[3]};
                pmA += fast_silu2(a01) * w32;
                pmB += fast_silu2(a23) * w32;
            }
            float pm0 = pmA[0], pm1 = pmA[1], pm2 = pmB[0], pm3 = pmB[1];

            // rotate-reduce across the 16-lane row (DPP, pure VALU)
            REDUCE16(pm0);
            REDUCE16(pm1);
            REDUCE16(pm2);
            REDUCE16(pm3);
            // group kg holds m for edges ebase + kg*4 + {0..3} in pm0..pm3

            if (lrow < 12) {
                float mval = (rsel == 0) ? pm0 : (rsel == 1) ? pm1
                           : (rsel == 2) ? pm2 : pm3;
                float cd = half ? cd1 : cd0;
                float em = half ? em1 : em0;
                int rnode = half ? rn1 : rn0;
                float val = cd * mval * em;
                atomicAdd(&agg[rnode * 3 + dim], val);
            }
        }
        buf ^= 1;
    }
}

// ---------------------------------------------------------------------------
// Kernel 3: out = (coord + agg/100) * node_mask
// ---------------------------------------------------------------------------
__global__ __launch_bounds__(256) void finalize_kernel(
    const float* __restrict__ coord, const float* __restrict__ agg,
    const float* __restrict__ node_mask, float* __restrict__ out)
{
    int i = blockIdx.x * 256 + threadIdx.x;
    if (i < N_NODES * 3) {
        out[i] = (coord[i] + agg[i] * 0.01f) * node_mask[i / 3];
    }
}

extern "C" void kernel_launch(void* const* d_in, const int* in_sizes, int n_in,
                              void* d_out, int out_size, void* d_ws, size_t ws_size,
                              hipStream_t stream) {
    const float* h          = (const float*)d_in[0];
    const float* coord      = (const float*)d_in[1];
    const int*   eidx       = (const int*)d_in[2];   // [2][N_EDGES] int32
    const float* coord_diff = (const float*)d_in[3];
    const float* edge_attr  = (const float*)d_in[4];
    const float* node_mask  = (const float*)d_in[5];
    const float* edge_mask  = (const float*)d_in[6];
    const float* W1 = (const float*)d_in[7];
    const float* b1 = (const float*)d_in[8];
    const float* W2 = (const float*)d_in[9];
    const float* b2 = (const float*)d_in[10];
    const float* W3 = (const float*)d_in[11];
    float* out = (float*)d_out;

    uint8_t* At = (uint8_t*)d_ws;                          // 6.4 MB
    uint8_t* Bt = At + (size_t)N_NODES * 128;              // 6.4 MB
    float*  agg = (float*)(Bt + (size_t)N_NODES * 128);    // 600 KB

    precompute_AB<<<(N_NODES + 255) / 256, 256, 0, stream>>>(h, W1, b1, At, Bt, agg);

    edge_kernel<<<512, 1024, 0, stream>>>(eidx, eidx + N_EDGES, edge_attr, edge_mask,
                                          coord_diff, W1, W2, b2, W3, At, Bt, agg);

    finalize_kernel<<<(N_NODES * 3 + 255) / 256, 256, 0, stream>>>(coord, agg, node_mask, out);
}

// Round 19
// 116.799 us; speedup vs baseline: 1.3683x; 1.0258x over previous
//
#include <hip/hip_runtime.h>
#include <hip/hip_bf16.h>
#include <stdint.h>
#include <string.h>

#define N_NODES 50000
#define N_EDGES 1000000
#define HIDDEN 128

using short8  = __attribute__((ext_vector_type(8))) short;
using floatx4 = __attribute__((ext_vector_type(4))) float;
using floatx2 = __attribute__((ext_vector_type(2))) float;
using uintx2  = __attribute__((ext_vector_type(2))) unsigned int;

__device__ __forceinline__ float bf2f(uint16_t u) {
    return __uint_as_float(((uint32_t)u) << 16);
}
__device__ __forceinline__ uint16_t f2bf(float f) {
    uint32_t x = __float_as_uint(f);
    return (uint16_t)((x + 0x7FFFu + ((x >> 16) & 1u)) >> 16);
}
__device__ __forceinline__ uint32_t cvt_pk_bf16(float lo, float hi) {
    uint32_t r;
    asm("v_cvt_pk_bf16_f32 %0, %1, %2" : "=v"(r) : "v"(lo), "v"(hi));
    return r;
}
// single-trans silu on a PAIR: packed ops (v_pk_mul/fma) for everything but
// the 2 rsq. sigmoid(x)=0.5(1+tanh(x/2)), tanh(y)~=y*rsqrt(1+y^2).
__device__ __forceinline__ floatx2 fast_silu2(floatx2 x) {
    floatx2 t = x * 0.5f;
    floatx2 s = t * t + 1.0f;
    floatx2 r;
    r[0] = __builtin_amdgcn_rsqf(s[0]);
    r[1] = __builtin_amdgcn_rsqf(s[1]);
    floatx2 u = t * r;
    return u * t + t;
}
// one f32 -> one fp8 e4m3 byte (gfx950 OCP format)
__device__ __forceinline__ uint8_t f2fp8(float v) {
    uint32_t p = __builtin_amdgcn_cvt_pk_fp8_f32(v, v, 0u, false);
    return (uint8_t)(p & 0xffu);
}

// channel permutation for At/Bt storage: c = kk*32 + kg*8 + j  ->  kg*32 + kk*8 + j
__device__ __forceinline__ int perm_c(int c) {
    return ((c >> 3) & 3) * 32 + ((c >> 5) << 3) + (c & 7);
}

// DPP rotate-add within each 16-lane row (pure VALU, no LDS pipe)
template <int CTRL>
__device__ __forceinline__ float row_ror_add(float v) {
    return v + __int_as_float(__builtin_amdgcn_update_dpp(
        0, __float_as_int(v), CTRL, 0xf, 0xf, false));
}
#define REDUCE16(v)                  \
    v = row_ror_add<0x121>(v);       \
    v = row_ror_add<0x122>(v);       \
    v = row_ror_add<0x124>(v);       \
    v = row_ror_add<0x128>(v);

// ---------------------------------------------------------------------------
// Kernel 1: At[n][k] -> fp8, Bt[n][k] -> fp8 (perm_c channel order).
// Coalesced W1 staging + LDS-staged coalesced output stores + agg zeroing.
// UNCHANGED this round (control).
// ---------------------------------------------------------------------------
__global__ __launch_bounds__(256) void precompute_AB(
    const float* __restrict__ h, const float* __restrict__ W1,
    const float* __restrict__ b1,
    uint8_t* __restrict__ At, uint8_t* __restrict__ Bt,
    float* __restrict__ agg)
{
    __shared__ uint16_t w1t[256 * 128];      // [c][j] bf16, XOR-swizzled, 64 KB
    __shared__ uint8_t s_out[4][16][256];    // [wave][node_local][col], 16 KB
    int t = threadIdx.x;

    // zero agg (was a separate hipMemsetAsync dispatch)
    for (int i = blockIdx.x * 256 + t; i < N_NODES * 3; i += gridDim.x * 256)
        agg[i] = 0.0f;

    // coalesced W1 staging: lanes carry consecutive c; one 16B ds_write each
    for (int item = t; item < 256 * 16; item += 256) {
        int c  = item & 255;
        int jb = item >> 8;              // j = jb*8 .. jb*8+7
        uint16_t vals[8];
#pragma unroll
        for (int jj = 0; jj < 8; ++jj) {
            int j = jb * 8 + jj;
            float v = (c < 128) ? W1[j * 128 + c]
                                : W1[(128 + j) * 128 + (c - 128)];
            vals[jj] = f2bf(v);
        }
        int byte_off = (c << 8) + (jb << 4);
        byte_off ^= ((c & 7) << 4);
        *(short8*)((char*)w1t + byte_off) = *(const short8*)vals;
    }
    __syncthreads();

    int wave = t >> 6, lane = t & 63;
    int lrow = lane & 15, kg = lane >> 4;

    for (int g = 0; g < 4; ++g) {
        int nodeBase = blockIdx.x * 256 + g * 64 + wave * 16;
        if (nodeBase >= N_NODES) break;
        int node = nodeBase + lrow;
        int nclamp = node < N_NODES ? node : N_NODES - 1;
        const float* hrow = h + (size_t)nclamp * 128;

        short8 afrag[4];
#pragma unroll
        for (int kk = 0; kk < 4; ++kk) {
            int k0 = kk * 32 + kg * 8;
            float4 f0 = *(const float4*)(hrow + k0);
            float4 f1 = *(const float4*)(hrow + k0 + 4);
            short8 a;
            uint32_t* ap = (uint32_t*)&a;
            ap[0] = cvt_pk_bf16(f0.x, f0.y);
            ap[1] = cvt_pk_bf16(f0.z, f0.w);
            ap[2] = cvt_pk_bf16(f1.x, f1.y);
            ap[3] = cvt_pk_bf16(f1.z, f1.w);
            afrag[kk] = a;
        }

        for (int nt = 0; nt < 16; ++nt) {
            floatx4 acc = {0.f, 0.f, 0.f, 0.f};
            int c = nt * 16 + lrow;
#pragma unroll
            for (int kk = 0; kk < 4; ++kk) {
                int byte_off = (c << 8) + ((kk * 32 + kg * 8) << 1);
                byte_off ^= ((c & 7) << 4);
                short8 b = *(const short8*)((const char*)w1t + byte_off);
                acc = __builtin_amdgcn_mfma_f32_16x16x32_bf16(afrag[kk], b, acc, 0, 0, 0);
            }
#pragma unroll
            for (int r = 0; r < 4; ++r) {
                int nl = kg * 4 + r;
                float v = acc[r];
                if (c < 128) {
                    s_out[wave][nl][perm_c(c)] = f2fp8(v + b1[c]);
                } else {
                    s_out[wave][nl][128 + perm_c(c - 128)] = f2fp8(v);
                }
            }
        }

        // wave-local coalesced store: 16 nodes x 256B; lanes 0-7 cover the
        // node's At row (128B), lanes 8-15 the Bt row.
#pragma unroll
        for (int it = 0; it < 4; ++it) {
            int nl = it * 4 + kg;            // node_local 0..15
            int colb = lrow * 16;            // 16B chunk within the 256 cols
            int onode = nodeBase + nl;
            if (onode < N_NODES) {
                uint4 v4 = *(const uint4*)&s_out[wave][nl][colb];
                if (colb < 128)
                    *(uint4*)(At + (size_t)onode * 128 + colb) = v4;
                else
                    *(uint4*)(Bt + (size_t)onode * 128 + (colb - 128)) = v4;
            }
        }
    }
}

// ---------------------------------------------------------------------------
// Kernel 2: per-edge fused MLP with fp8 x fp8 layer-2 MFMA.
// w2t fp8 lane-linear (16 KB, was 32 KB bf16): each B-fragment is ONE
// ds_read_b64 (was b128) -> ~30% less LDS-pipe work (co-limiting with VALU).
// A-fragments packed to fp8 once per kk into a uintx2 pair, bitcast at the
// MFMA call (round-11's 108-VGPR blowup came from in-loop long long
// shift/or construction - excised here). Layout/numerics verified r11.
// VGPR must stay <=64.
// ---------------------------------------------------------------------------
__global__ __launch_bounds__(1024) void edge_kernel(
    const int* __restrict__ rowIdx, const int* __restrict__ colIdx,
    const float* __restrict__ edge_attr, const float* __restrict__ edge_mask,
    const float* __restrict__ coord_diff,
    const float* __restrict__ W1, const float* __restrict__ W2,
    const float* __restrict__ b2, const float* __restrict__ W3,
    const uint8_t* __restrict__ At, const uint8_t* __restrict__ Bt,
    float* __restrict__ agg)
{
    __shared__ uint8_t w2t[128 * 128];           // [nt][kk][lane][8] fp8, 16 KB
    __shared__ float s_w1e[128], s_b2[128], s_w3[128];
    __shared__ int s_idx[2][16][64];             // [buf][wave][0-31 row | 32-63 col], 8 KB
    int t = threadIdx.x;
    for (int idx = t; idx < 128 * 128; idx += 1024) {
        int j    = idx & 7;
        int ln   = (idx >> 3) & 63;
        int kkq  = (idx >> 9) & 3;
        int ntq  = idx >> 11;
        int n = ntq * 16 + (ln & 15);
        int k = kkq * 32 + (ln >> 4) * 8 + j;
        w2t[idx] = f2fp8(W2[k * 128 + n]);
    }
    if (t < 128) { s_w1e[t] = W1[256 * 128 + t]; s_b2[t] = b2[t]; s_w3[t] = W3[t]; }
    __syncthreads();

    int wave = t >> 6, lane = t & 63;
    int lrow = lane & 15, kg = lane >> 4;

    const int numPairs = N_EDGES / 32;           // 31250
    int wavesTotal = gridDim.x * 16;
    int waveId = blockIdx.x * 16 + wave;
    if (waveId >= numPairs) return;

    // per-lane epilogue geometry (loop-invariant)
    int rsel = lrow / 3;                         // 0..5 (only 0..3 used)
    int dim  = lrow - rsel * 3;

    // ---- prologue: prefetch pair-0 indices into buf 0, wait once ----
    {
        int eb0 = waveId * 32;
        const int* gsrc = (lane < 32) ? (rowIdx + eb0 + lane)
                                      : (colIdx + eb0 + (lane & 31));
        __builtin_amdgcn_global_load_lds(
            (const __attribute__((address_space(1))) void*)gsrc,
            (__attribute__((address_space(3))) void*)&s_idx[0][wave][0], 4, 0, 0);
        __builtin_amdgcn_s_waitcnt(0x0F70);      // vmcnt(0)
    }

    int buf = 0;
    for (int pair = waveId; pair < numPairs; pair += wavesTotal) {
        // wait current buf's prefetch (skip the 2 in-flight atomics)
        __builtin_amdgcn_s_waitcnt(0x0F72);      // vmcnt(2)
        __builtin_amdgcn_sched_barrier(0);
        const int* mi = &s_idx[buf][wave][0];
        int r0 = mi[lrow],      c0 = mi[32 + lrow];
        int r1 = mi[16 + lrow], c1 = mi[48 + lrow];

        // prefetch next pair into the other buffer
        int nextp = pair + wavesTotal;
        if (nextp < numPairs) {
            int ebn = nextp * 32;
            const int* gsrc = (lane < 32) ? (rowIdx + ebn + lane)
                                          : (colIdx + ebn + (lane & 31));
            __builtin_amdgcn_global_load_lds(
                (const __attribute__((address_space(1))) void*)gsrc,
                (__attribute__((address_space(3))) void*)&s_idx[buf ^ 1][wave][0], 4, 0, 0);
        }

        int ebase0 = pair * 32;
        int ebase1 = ebase0 + 16;
        float attr0 = edge_attr[ebase0 + lrow];
        float attr1 = edge_attr[ebase1 + lrow];

        // ---- hoisted epilogue operands (all lanes, clamped; used if lrow<12) ----
        int sidx = kg * 4 + rsel;                        // 0..19; valid slot 0..15
        int eg0 = ebase0 + sidx;
        int eg1 = ebase1 + sidx;
        int eg0c = eg0 < N_EDGES - 1 ? eg0 : N_EDGES - 1;
        int eg1c = eg1 < N_EDGES - 1 ? eg1 : N_EDGES - 1;
        float cd0 = coord_diff[eg0c * 3 + dim];
        float em0 = edge_mask[eg0c];
        float cd1 = coord_diff[eg1c * 3 + dim];
        float em1 = edge_mask[eg1c];
        int sclamp = sidx < 16 ? sidx : 15;
        int rn0 = mi[sclamp];
        int rn1 = mi[16 + sclamp];

        // ---- all 8 gathers up front (half-0 first) ----
        const uint8_t* ar0 = At + (size_t)r0 * 128 + kg * 32;
        const uint8_t* br0 = Bt + (size_t)c0 * 128 + kg * 32;
        const uint8_t* ar1 = At + (size_t)r1 * 128 + kg * 32;
        const uint8_t* br1 = Bt + (size_t)c1 * 128 + kg * 32;
        uint4 la0 = *(const uint4*)(ar0);
        uint4 ha0 = *(const uint4*)(ar0 + 16);
        uint4 lb0 = *(const uint4*)(br0);
        uint4 hb0 = *(const uint4*)(br0 + 16);
        uint4 la1 = *(const uint4*)(ar1);
        uint4 ha1 = *(const uint4*)(ar1 + 16);
        uint4 lb1 = *(const uint4*)(br1);
        uint4 hb1 = *(const uint4*)(br1 + 16);

#pragma unroll
        for (int half = 0; half < 2; ++half) {
            float attr = half ? attr1 : attr0;
            uint4 la = half ? la1 : la0, ha = half ? ha1 : ha0;
            uint4 lb = half ? lb1 : lb0, hb = half ? hb1 : hb0;
            floatx2 attr2 = {attr, attr};

            // ---- layer 1: fp8 rows -> packed silu -> fp8 A-fragments ----
            uintx2 aw[4];
#pragma unroll
            for (int kk = 0; kk < 4; ++kk) {
                int k0 = kk * 32 + kg * 8;
                uint32_t wa0 = (kk == 0) ? la.x : (kk == 1) ? la.z : (kk == 2) ? ha.x : ha.z;
                uint32_t wa1 = (kk == 0) ? la.y : (kk == 1) ? la.w : (kk == 2) ? ha.y : ha.w;
                uint32_t wb0 = (kk == 0) ? lb.x : (kk == 1) ? lb.z : (kk == 2) ? hb.x : hb.z;
                uint32_t wb1 = (kk == 0) ? lb.y : (kk == 1) ? lb.w : (kk == 2) ? hb.y : hb.w;
                floatx2 pa0 = __builtin_amdgcn_cvt_pk_f32_fp8(wa0, false);
                floatx2 pa1 = __builtin_amdgcn_cvt_pk_f32_fp8(wa0, true);
                floatx2 pa2 = __builtin_amdgcn_cvt_pk_f32_fp8(wa1, false);
                floatx2 pa3 = __builtin_amdgcn_cvt_pk_f32_fp8(wa1, true);
                floatx2 pb0 = __builtin_amdgcn_cvt_pk_f32_fp8(wb0, false);
                floatx2 pb1 = __builtin_amdgcn_cvt_pk_f32_fp8(wb0, true);
                floatx2 pb2 = __builtin_amdgcn_cvt_pk_f32_fp8(wb1, false);
                floatx2 pb3 = __builtin_amdgcn_cvt_pk_f32_fp8(wb1, true);
                const floatx2* wq = (const floatx2*)(&s_w1e[k0]);
                floatx2 y0 = fast_silu2(pa0 + pb0 + attr2 * wq[0]);
                floatx2 y1 = fast_silu2(pa1 + pb1 + attr2 * wq[1]);
                floatx2 y2 = fast_silu2(pa2 + pb2 + attr2 * wq[2]);
                floatx2 y3 = fast_silu2(pa3 + pb3 + attr2 * wq[3]);
                uint32_t u0 = __builtin_amdgcn_cvt_pk_fp8_f32(y0[0], y0[1], 0u, false);
                u0 = __builtin_amdgcn_cvt_pk_fp8_f32(y1[0], y1[1], u0, true);
                uint32_t u1 = __builtin_amdgcn_cvt_pk_fp8_f32(y2[0], y2[1], 0u, false);
                u1 = __builtin_amdgcn_cvt_pk_fp8_f32(y3[0], y3[1], u1, true);
                aw[kk][0] = u0;
                aw[kk][1] = u1;
            }

            // ---- layer 2 (fp8 x fp8 MFMA, ds_read_b64 B) + packed epilogue ----
            floatx2 pmA = {0.f, 0.f}, pmB = {0.f, 0.f};
#pragma unroll
            for (int nt = 0; nt < 8; ++nt) {
                int n = nt * 16 + lrow;
                float b2v = s_b2[n];
                floatx4 acc = {b2v, b2v, b2v, b2v};
#pragma unroll
                for (int kk = 0; kk < 4; ++kk) {
                    long long bv;
                    memcpy(&bv, w2t + (((nt * 4 + kk) * 64 + lane) << 3), 8);
                    long long av;
                    uintx2 a2 = aw[kk];
                    memcpy(&av, &a2, 8);
                    acc = __builtin_amdgcn_mfma_f32_16x16x32_fp8_fp8(av, bv, acc, 0, 0, 0);
                }
                float w3v = s_w3[n];
                floatx2 w32 = {w3v, w3v};
                floatx2 a01 = {acc[0], acc[1]};
                floatx2 a23 = {acc[2], acc[3]};
                pmA += fast_silu2(a01) * w32;
                pmB += fast_silu2(a23) * w32;
            }
            float pm0 = pmA[0], pm1 = pmA[1], pm2 = pmB[0], pm3 = pmB[1];

            // rotate-reduce across the 16-lane row (DPP, pure VALU)
            REDUCE16(pm0);
            REDUCE16(pm1);
            REDUCE16(pm2);
            REDUCE16(pm3);
            // group kg holds m for edges ebase + kg*4 + {0..3} in pm0..pm3

            if (lrow < 12) {
                float mval = (rsel == 0) ? pm0 : (rsel == 1) ? pm1
                           : (rsel == 2) ? pm2 : pm3;
                float cd = half ? cd1 : cd0;
                float em = half ? em1 : em0;
                int rnode = half ? rn1 : rn0;
                float val = cd * mval * em;
                atomicAdd(&agg[rnode * 3 + dim], val);
            }
        }
        buf ^= 1;
    }
}

// ---------------------------------------------------------------------------
// Kernel 3: out = (coord + agg/100) * node_mask
// ---------------------------------------------------------------------------
__global__ __launch_bounds__(256) void finalize_kernel(
    const float* __restrict__ coord, const float* __restrict__ agg,
    const float* __restrict__ node_mask, float* __restrict__ out)
{
    int i = blockIdx.x * 256 + threadIdx.x;
    if (i < N_NODES * 3) {
        out[i] = (coord[i] + agg[i] * 0.01f) * node_mask[i / 3];
    }
}

extern "C" void kernel_launch(void* const* d_in, const int* in_sizes, int n_in,
                              void* d_out, int out_size, void* d_ws, size_t ws_size,
                              hipStream_t stream) {
    const float* h          = (const float*)d_in[0];
    const float* coord      = (const float*)d_in[1];
    const int*   eidx       = (const int*)d_in[2];   // [2][N_EDGES] int32
    const float* coord_diff = (const float*)d_in[3];
    const float* edge_attr  = (const float*)d_in[4];
    const float* node_mask  = (const float*)d_in[5];
    const float* edge_mask  = (const float*)d_in[6];
    const float* W1 = (const float*)d_in[7];
    const float* b1 = (const float*)d_in[8];
    const float* W2 = (const float*)d_in[9];
    const float* b2 = (const float*)d_in[10];
    const float* W3 = (const float*)d_in[11];
    float* out = (float*)d_out;

    uint8_t* At = (uint8_t*)d_ws;                          // 6.4 MB
    uint8_t* Bt = At + (size_t)N_NODES * 128;              // 6.4 MB
    float*  agg = (float*)(Bt + (size_t)N_NODES * 128);    // 600 KB

    precompute_AB<<<(N_NODES + 255) / 256, 256, 0, stream>>>(h, W1, b1, At, Bt, agg);

    edge_kernel<<<512, 1024, 0, stream>>>(eidx, eidx + N_EDGES, edge_attr, edge_mask,
                                          coord_diff, W1, W2, b2, W3, At, Bt, agg);

    finalize_kernel<<<(N_NODES * 3 + 255) / 256, 256, 0, stream>>>(coord, agg, node_mask, out);
}